// Round 9
// baseline (2124.743 us; speedup 1.0000x reference)
//
#include <hip/hip_runtime.h>

#define NN 50000
#define NE 10000
#define NNZC 200000
#define OBSD 128
#define LATD 256
#define NSTEPS 8

typedef unsigned short u16;
typedef unsigned char u8;
typedef __attribute__((ext_vector_type(8))) short bf16x8;
typedef __attribute__((ext_vector_type(4))) float f32x4;
typedef __attribute__((ext_vector_type(2))) float f32x2;
typedef __attribute__((ext_vector_type(4))) u16 us4;
typedef __attribute__((ext_vector_type(8))) u16 us8;
typedef __attribute__((ext_vector_type(16))) u16 us16;
typedef __attribute__((ext_vector_type(2))) unsigned int u32x2;
typedef __attribute__((ext_vector_type(4))) unsigned int u32x4;

__device__ __forceinline__ u16 f2b(float f) {
  unsigned int u = __builtin_bit_cast(unsigned int, f);
  u = (u + 0x7FFFu + ((u >> 16) & 1u)) >> 16;
  return (u16)u;
}
__device__ __forceinline__ float b2f(u16 h) {
  unsigned int u = ((unsigned int)h) << 16;
  return __builtin_bit_cast(float, u);
}
__device__ __forceinline__ float fast_tanh(float x) {
  float e = __expf(2.0f * x);
  return 1.0f - 2.0f / (e + 1.0f);
}

// ---- OCP e4m3 fp8 pack/unpack (HW converts, gfx950) ----
__device__ __forceinline__ void fp8_dec4(unsigned int w, float* o) {
  f32x2 a = __builtin_amdgcn_cvt_pk_f32_fp8((int)w, false);
  f32x2 b = __builtin_amdgcn_cvt_pk_f32_fp8((int)w, true);
  o[0] = a[0]; o[1] = a[1]; o[2] = b[0]; o[3] = b[1];
}
__device__ __forceinline__ void fp8_dec16(u32x4 w, float* o) {
#pragma unroll
  for (int q = 0; q < 4; ++q) fp8_dec4(w[q], o + q * 4);
}
__device__ __forceinline__ unsigned int fp8_enc4(const float* v) {
  int lo = __builtin_amdgcn_cvt_pk_fp8_f32(v[0], v[1], 0, false);
  lo = __builtin_amdgcn_cvt_pk_fp8_f32(v[2], v[3], lo, true);
  return (unsigned int)lo;
}

typedef __attribute__((address_space(1))) const unsigned int GU32;
typedef __attribute__((address_space(3))) unsigned int LU32;
__device__ __forceinline__ void async16(const void* g, void* l) {
  __builtin_amdgcn_global_load_lds((GU32*)g, (LU32*)l, 16, 0, 0);
}

// ---------------- CSR build ----------------

__global__ void count_kernel(const int* __restrict__ ni, const int* __restrict__ ei,
                             int* __restrict__ cnt_n, int* __restrict__ cnt_e, int nnz) {
  int i = blockIdx.x * blockDim.x + threadIdx.x;
  if (i < nnz) {
    atomicAdd(&cnt_n[ni[i]], 1);
    atomicAdd(&cnt_e[ei[i]], 1);
  }
}

__global__ __launch_bounds__(1024) void scan1_kernel(const int* __restrict__ cnt,
                                                     int* __restrict__ off,
                                                     int* __restrict__ bsum, int n) {
  __shared__ int ws[16];
  const int tid = threadIdx.x;
  const int lane = tid & 63, w = tid >> 6;
  const int i = blockIdx.x * 1024 + tid;
  int v = (i < n) ? cnt[i] : 0;
  int s = v;
#pragma unroll
  for (int d = 1; d < 64; d <<= 1) {
    int t2 = __shfl_up(s, d);
    if (lane >= d) s += t2;
  }
  if (lane == 63) ws[w] = s;
  __syncthreads();
  if (w == 0) {
    int x = (lane < 16) ? ws[lane] : 0;
#pragma unroll
    for (int d = 1; d < 16; d <<= 1) {
      int t2 = __shfl_up(x, d);
      if (lane >= d) x += t2;
    }
    if (lane < 16) ws[lane] = x;
  }
  __syncthreads();
  const int base = w ? ws[w - 1] : 0;
  if (i < n) off[i] = base + s - v;
  if (tid == 0) bsum[blockIdx.x] = ws[15];
}

__global__ void scan2_kernel(int* __restrict__ bsum, int nb) {
  const int lane = threadIdx.x;
  int v = (lane < nb) ? bsum[lane] : 0;
  int s = v;
#pragma unroll
  for (int d = 1; d < 64; d <<= 1) {
    int t2 = __shfl_up(s, d);
    if (lane >= d) s += t2;
  }
  if (lane < nb) bsum[lane] = s - v;
  if (lane == 63) bsum[nb] = s;
}

__global__ void scan3_kernel(const int* __restrict__ cnt, int* __restrict__ off,
                             int* __restrict__ cur, float* __restrict__ recip,
                             const int* __restrict__ bsum, int n) {
  const int i = blockIdx.x * blockDim.x + threadIdx.x;
  if (i < n) {
    const int o = off[i] + bsum[i >> 10];
    off[i] = o;
    cur[i] = o;
    recip[i] = 1.0f / fmaxf((float)cnt[i], 1.0f);
  }
  if (i == 0) off[n] = bsum[(n + 1023) >> 10];
}

__global__ void fill_kernel(const int* __restrict__ ni, const int* __restrict__ ei,
                            int* __restrict__ cur_n, int* __restrict__ cur_e,
                            int* __restrict__ lst_n, int* __restrict__ lst_e, int nnz) {
  int i = blockIdx.x * blockDim.x + threadIdx.x;
  if (i < nnz) {
    int n = ni[i], e = ei[i];
    lst_e[atomicAdd(&cur_e[e], 1)] = n;
    lst_n[atomicAdd(&cur_n[n], 1)] = e;
  }
}

// ---------------- small prep ----------------

__global__ void transpose_kernel(const float* __restrict__ W, u16* __restrict__ WT, int K, int N) {
  int i = blockIdx.x * blockDim.x + threadIdx.x;
  if (i >= K * N) return;
  int k = i / N, n = i - k * N;
  WT[n * K + k] = f2b(W[i]);
}

__global__ void to_bf16_kernel(const float* __restrict__ src, u16* __restrict__ dst, int n) {
  int i = (blockIdx.x * blockDim.x + threadIdx.x) * 4;
  if (i >= n) return;
  float4 v = *reinterpret_cast<const float4*>(src + i);
  us4 o;
  o.x = f2b(v.x); o.y = f2b(v.y); o.z = f2b(v.z); o.w = f2b(v.w);
  *reinterpret_cast<us4*>(dst + i) = o;
}

// d = bne @ Wen + ben
__global__ void dvec_kernel(const float* __restrict__ bne, const float* __restrict__ Wen,
                            const float* __restrict__ ben, float* __restrict__ d) {
  const int j = threadIdx.x;
  float s = ben[j];
  for (int k = 0; k < LATD; ++k) s += bne[k] * Wen[k * LATD + j];
  d[j] = s;
}

// ---------------- fused edge gather-mean + GEMM(Wc): G = mean_e(src) @ Wc ----------------
// Block: 64 edge rows x full N=256, 4 waves (wave = one 64-col strip).
// LDS: A 64x256 bf16 (32KB, XOR slot swizzle s^=(row&3)); B single-buffered
// 256x32 bf16 chunk (16KB, pre-swizzled source + linear dest). 48KB -> 3 blocks/CU.
// SRC=0: bf16 rows (zhi). SRC=1: fp8 rows (k plane). OUT=0: Gb bf16; OUT=1: Gf8 fp8.

template <int SRC>
__global__ __launch_bounds__(256) void eg_kernel(
    const void* __restrict__ src, const int* __restrict__ off, const int* __restrict__ lst,
    const float* __restrict__ recip, const u16* __restrict__ BT,
    u16* __restrict__ Gb, u8* __restrict__ Gf8) {
  __shared__ u16 lA[64 * 256];   // 32KB
  __shared__ u16 lB[256 * 32];   // 16KB (one K-chunk)
  const int t = threadIdx.x;
  const int lane = t & 63, w = t >> 6;
  const int m0 = blockIdx.x * 64;

  // ---- gather-mean A rows into swizzled LDS ----
  if constexpr (SRC == 1) {
    const int gl = lane & 15;  // 16-lane groups, 4 rows per wave in parallel
    for (int it = 0; it < 4; ++it) {
      const int r = w * 16 + it * 4 + (lane >> 4);
      const int ge = m0 + r;
      float a[16] = {};
      if (ge < NE) {
        const int s = off[ge], e = off[ge + 1];
        int p = s;
        for (; p + 4 <= e; p += 4) {
          const int r0 = lst[p], r1 = lst[p + 1], r2 = lst[p + 2], r3 = lst[p + 3];
          const u32x4 w0 = *(const u32x4*)((const u8*)src + (size_t)r0 * LATD + gl * 16);
          const u32x4 w1 = *(const u32x4*)((const u8*)src + (size_t)r1 * LATD + gl * 16);
          const u32x4 w2 = *(const u32x4*)((const u8*)src + (size_t)r2 * LATD + gl * 16);
          const u32x4 w3 = *(const u32x4*)((const u8*)src + (size_t)r3 * LATD + gl * 16);
          float f[16];
          fp8_dec16(w0, f);
#pragma unroll
          for (int j = 0; j < 16; ++j) a[j] += f[j];
          fp8_dec16(w1, f);
#pragma unroll
          for (int j = 0; j < 16; ++j) a[j] += f[j];
          fp8_dec16(w2, f);
#pragma unroll
          for (int j = 0; j < 16; ++j) a[j] += f[j];
          fp8_dec16(w3, f);
#pragma unroll
          for (int j = 0; j < 16; ++j) a[j] += f[j];
        }
        for (; p < e; ++p) {
          const u32x4 wv = *(const u32x4*)((const u8*)src + (size_t)lst[p] * LATD + gl * 16);
          float f[16];
          fp8_dec16(wv, f);
#pragma unroll
          for (int j = 0; j < 16; ++j) a[j] += f[j];
        }
        const float rc = recip[ge];
#pragma unroll
        for (int j = 0; j < 16; ++j) a[j] *= rc;
      }
      // write 32B = two 16B slots, XOR-swizzled within 64B chunk
      const int ch = gl >> 1, s0 = (gl & 1) * 2;
      us8 o0, o1;
#pragma unroll
      for (int j = 0; j < 8; ++j) { o0[j] = f2b(a[j]); o1[j] = f2b(a[j + 8]); }
      char* rowb = (char*)lA + r * 512 + ch * 64;
      *(us8*)(rowb + ((s0 ^ (r & 3)) << 4)) = o0;
      *(us8*)(rowb + (((s0 + 1) ^ (r & 3)) << 4)) = o1;
    }
  } else {
    const int gl2 = lane & 31;  // 32-lane groups, 2 rows per wave in parallel
    for (int it = 0; it < 8; ++it) {
      const int r = w * 16 + it * 2 + (lane >> 5);
      const int ge = m0 + r;
      float a[8] = {};
      if (ge < NE) {
        const int s = off[ge], e = off[ge + 1];
        int p = s;
        for (; p + 4 <= e; p += 4) {
          const int r0 = lst[p], r1 = lst[p + 1], r2 = lst[p + 2], r3 = lst[p + 3];
          const us8 v0 = *(const us8*)((const u16*)src + (size_t)r0 * LATD + gl2 * 8);
          const us8 v1 = *(const us8*)((const u16*)src + (size_t)r1 * LATD + gl2 * 8);
          const us8 v2 = *(const us8*)((const u16*)src + (size_t)r2 * LATD + gl2 * 8);
          const us8 v3 = *(const us8*)((const u16*)src + (size_t)r3 * LATD + gl2 * 8);
#pragma unroll
          for (int j = 0; j < 8; ++j)
            a[j] += b2f(v0[j]) + b2f(v1[j]) + b2f(v2[j]) + b2f(v3[j]);
        }
        for (; p < e; ++p) {
          const us8 v = *(const us8*)((const u16*)src + (size_t)lst[p] * LATD + gl2 * 8);
#pragma unroll
          for (int j = 0; j < 8; ++j) a[j] += b2f(v[j]);
        }
        const float rc = recip[ge];
#pragma unroll
        for (int j = 0; j < 8; ++j) a[j] *= rc;
      }
      us8 o;
#pragma unroll
      for (int j = 0; j < 8; ++j) o[j] = f2b(a[j]);
      *(us8*)((char*)lA + r * 512 + (gl2 >> 2) * 64 + (((gl2 & 3) ^ (r & 3)) << 4)) = o;
    }
  }

  // ---- B staging setup (pre-swizzled source, linear LDS dest) ----
  const int srow = t >> 2;
  const int gslot = (t & 3) ^ ((srow >> 1) & 3);
  const u16* gB = BT + (size_t)srow * LATD + gslot * 8;
  char* lBd = (char*)lB + t * 16;

  const int lrow = lane & 15, kg = lane >> 4;
  f32x4 acc[4][4] = {};

  // ---- K loop: 8 chunks of 32, single-buffered B ----
  for (int c = 0; c < 8; ++c) {
#pragma unroll
    for (int q = 0; q < 4; ++q)
      async16(gB + (size_t)q * 64 * LATD + c * 32, lBd + q * 4096);
    __syncthreads();
    bf16x8 af[4], bg[4];
#pragma unroll
    for (int i = 0; i < 4; ++i) {
      const int rA = i * 16 + lrow;
      af[i] = *(const bf16x8*)((const char*)lA + rA * 512 + c * 64 + ((kg ^ (rA & 3)) << 4));
      const int rB = w * 64 + i * 16 + lrow;
      bg[i] = *(const bf16x8*)((const char*)lB + rB * 64 + ((kg ^ ((rB >> 1) & 3)) << 4));
    }
#pragma unroll
    for (int i = 0; i < 4; ++i)
#pragma unroll
      for (int j = 0; j < 4; ++j)
        acc[i][j] = __builtin_amdgcn_mfma_f32_16x16x32_bf16(af[i], bg[j], acc[i][j], 0, 0, 0);
    __syncthreads();
  }

  // ---- staged epilogue (wave-private region in lA; all GEMM reads done) ----
  float* stage = (float*)(void*)lA + w * (16 * 66);
  const int rr = lane >> 3;
  const int c0 = (lane & 7) * 8;

#pragma unroll
  for (int ti = 0; ti < 4; ++ti) {
#pragma unroll
    for (int tj = 0; tj < 4; ++tj)
#pragma unroll
      for (int j = 0; j < 4; ++j)
        stage[(kg * 4 + j) * 66 + tj * 16 + lrow] = acc[ti][tj][j];
#pragma unroll
    for (int pass = 0; pass < 2; ++pass) {
      const int r = pass * 8 + rr;
      const int gr = m0 + ti * 16 + r;
      if (gr >= NE) continue;
      const int gc = w * 64 + c0;
      const size_t idx = (size_t)gr * LATD + gc;
      float v[8];
      *(float4*)v = *(const float4*)&stage[r * 66 + c0];
      *(float4*)(v + 4) = *(const float4*)&stage[r * 66 + c0 + 4];
      if constexpr (SRC == 0) {
        us8 o;
#pragma unroll
        for (int e2 = 0; e2 < 8; ++e2) o[e2] = f2b(v[e2]);
        *(us8*)(Gb + idx) = o;
      } else {
        u32x2 kp;
        kp[0] = fp8_enc4(v);
        kp[1] = fp8_enc4(v + 4);
        *(u32x2*)(Gf8 + idx) = kp;
      }
    }
  }
}

// ---------------- fused node-gather + RK epilogue ----------------

template <int STAGE>
__global__ __launch_bounds__(256) void aggn_epi_kernel(
    const void* __restrict__ G, const int* __restrict__ off, const int* __restrict__ lst,
    const float* __restrict__ recip, const float* __restrict__ dvec,
    u16* __restrict__ ub, const u8* __restrict__ k2s, const u8* __restrict__ k3s,
    u8* __restrict__ kout8, u16* __restrict__ zhi, float c) {
  constexpr int GW = (STAGE == 0) ? 32 : 16;
  constexpr int EPL = LATD / GW;  // 8 or 16
  const int t = threadIdx.x;
  const int gl = t & (GW - 1);
  const int node = blockIdx.x * (256 / GW) + (t / GW);
  if (node >= NN) return;
  const int s = off[node], e = off[node + 1];
  float v[EPL] = {};
  int p = s;
  if constexpr (STAGE == 0) {
    for (; p + 2 <= e; p += 2) {
      const int r0 = lst[p], r1 = lst[p + 1];
      const us8 g0 = *(const us8*)((const u16*)G + (size_t)r0 * LATD + gl * 8);
      const us8 g1 = *(const us8*)((const u16*)G + (size_t)r1 * LATD + gl * 8);
#pragma unroll
      for (int j = 0; j < 8; ++j) v[j] += b2f(g0[j]) + b2f(g1[j]);
    }
    for (; p < e; ++p) {
      const us8 g = *(const us8*)((const u16*)G + (size_t)lst[p] * LATD + gl * 8);
#pragma unroll
      for (int j = 0; j < 8; ++j) v[j] += b2f(g[j]);
    }
  } else {
    for (; p + 2 <= e; p += 2) {
      const int r0 = lst[p], r1 = lst[p + 1];
      const u32x4 w0 = *(const u32x4*)((const u8*)G + (size_t)r0 * LATD + gl * 16);
      const u32x4 w1 = *(const u32x4*)((const u8*)G + (size_t)r1 * LATD + gl * 16);
      float f[16];
      fp8_dec16(w0, f);
#pragma unroll
      for (int j = 0; j < 16; ++j) v[j] += f[j];
      fp8_dec16(w1, f);
#pragma unroll
      for (int j = 0; j < 16; ++j) v[j] += f[j];
    }
    for (; p < e; ++p) {
      const u32x4 w = *(const u32x4*)((const u8*)G + (size_t)lst[p] * LATD + gl * 16);
      float f[16];
      fp8_dec16(w, f);
#pragma unroll
      for (int j = 0; j < 16; ++j) v[j] += f[j];
    }
  }
  const float rc = recip[node];
  const size_t base = (size_t)node * LATD + gl * EPL;
  const float dt6 = 0.125f / 6.0f;

  if constexpr (STAGE == 0) {
    float kv[8];
    us8 uo;
#pragma unroll
    for (int j = 0; j < 8; ++j) {
      const float u = v[j] * rc + dvec[gl * 8 + j];
      uo[j] = f2b(u);
      kv[j] = fast_tanh(u);
    }
    *(us8*)(ub + base) = uo;
    u32x2 kp;
    kp[0] = fp8_enc4(kv);
    kp[1] = fp8_enc4(kv + 4);
    *(u32x2*)(kout8 + base) = kp;
  } else if constexpr (STAGE == 1) {
    const us16 uv = *(const us16*)(ub + base);
    float kv[16];
#pragma unroll
    for (int j = 0; j < 16; ++j)
      kv[j] = fast_tanh(b2f(uv[j]) + c * (v[j] * rc));
    u32x4 kp;
#pragma unroll
    for (int q = 0; q < 4; ++q) kp[q] = fp8_enc4(kv + q * 4);
    *(u32x4*)(kout8 + base) = kp;
  } else {  // STAGE 3
    const us16 uv = *(const us16*)(ub + base);
    const u32x4 w2 = *(const u32x4*)(k2s + base);
    const u32x4 w3 = *(const u32x4*)(k3s + base);
    const us16 zh = *(const us16*)(zhi + base);
    float f2[16], f3[16];
    fp8_dec16(w2, f2);
    fp8_dec16(w3, f3);
    us16 ho;
#pragma unroll
    for (int j = 0; j < 16; ++j) {
      const float u = b2f(uv[j]);
      const float k1 = fast_tanh(u);
      const float k4 = fast_tanh(u + c * (v[j] * rc));
      const float zn = b2f(zh[j]) + dt6 * (k1 + 2.0f * f2[j] + 2.0f * f3[j] + k4);
      ho[j] = f2b(zn);
    }
    *(us16*)(zhi + base) = ho;
  }
}

// ---------------- MFMA GEMM with LDS-staged coalesced epilogue (enc/dec/prep) ----------------

enum { EPI_RELU_BF16, EPI_BF16, EPI_F32 };

template <int MODE>
__global__ __launch_bounds__(256) void gemm_kernel(
    const u16* __restrict__ A, const u16* __restrict__ BT, const float* __restrict__ bias,
    int M, int N, int K,
    u16* __restrict__ outb, float* __restrict__ outf) {
  __shared__ char smem[4 * 16 * 66 * 4];
  u16* lA = (u16*)smem;
  u16* lB = (u16*)(smem + 8192);
  const int t = threadIdx.x;
  const int m0 = blockIdx.x * 128, n0 = blockIdx.y * 128;
  const int srow = t >> 2;
  const int gslot = (t & 3) ^ ((srow >> 1) & 3);

  int ar0 = m0 + srow;      if (ar0 > M - 1) ar0 = M - 1;
  int ar1 = m0 + srow + 64; if (ar1 > M - 1) ar1 = M - 1;
  const u16* gA0 = A + (size_t)ar0 * K + gslot * 8;
  const u16* gA1 = A + (size_t)ar1 * K + gslot * 8;
  const u16* gB0 = BT + (size_t)(n0 + srow) * K + gslot * 8;
  const u16* gB1 = BT + (size_t)(n0 + srow + 64) * K + gslot * 8;
  char* lAd0 = (char*)lA + t * 16; char* lAd1 = lAd0 + 4096;
  char* lBd0 = (char*)lB + t * 16; char* lBd1 = lBd0 + 4096;

  const int lane = t & 63, wid = t >> 6;
  const int wm = wid >> 1, wn = wid & 1;
  const int lrow = lane & 15, kg = lane >> 4;

  f32x4 acc[4][4] = {};
  const char* lAb = (const char*)lA;
  const char* lBb = (const char*)lB;

  for (int kk = 0; kk < K; kk += 32) {
    async16(gA0 + kk, lAd0);
    async16(gA1 + kk, lAd1);
    async16(gB0 + kk, lBd0);
    async16(gB1 + kk, lBd1);
    __syncthreads();
    bf16x8 af[4], bg[4];
#pragma unroll
    for (int i = 0; i < 4; ++i) {
      int rA = wm * 64 + i * 16 + lrow;
      af[i] = *(const bf16x8*)(lAb + rA * 64 + (((kg ^ (rA >> 1)) & 3) << 4));
      int rB = wn * 64 + i * 16 + lrow;
      bg[i] = *(const bf16x8*)(lBb + rB * 64 + (((kg ^ (rB >> 1)) & 3) << 4));
    }
#pragma unroll
    for (int i = 0; i < 4; ++i)
#pragma unroll
      for (int j = 0; j < 4; ++j)
        acc[i][j] = __builtin_amdgcn_mfma_f32_16x16x32_bf16(af[i], bg[j], acc[i][j], 0, 0, 0);
    __syncthreads();
  }

  float* stage = (float*)smem + wid * (16 * 66);
  const int rr = lane >> 3;
  const int c0 = (lane & 7) * 8;

#pragma unroll
  for (int ti = 0; ti < 4; ++ti) {
#pragma unroll
    for (int tj = 0; tj < 4; ++tj) {
      const float bv = bias[n0 + wn * 64 + tj * 16 + lrow];
#pragma unroll
      for (int j = 0; j < 4; ++j)
        stage[(kg * 4 + j) * 66 + tj * 16 + lrow] = acc[ti][tj][j] + bv;
    }
#pragma unroll
    for (int pass = 0; pass < 2; ++pass) {
      const int r = pass * 8 + rr;
      const int gr = m0 + wm * 64 + ti * 16 + r;
      if (gr >= M) continue;
      const int gc = n0 + wn * 64 + c0;
      const size_t idx = (size_t)gr * N + gc;
      float v[8];
      *(float4*)v = *(const float4*)&stage[r * 66 + c0];
      *(float4*)(v + 4) = *(const float4*)&stage[r * 66 + c0 + 4];

      if constexpr (MODE == EPI_RELU_BF16 || MODE == EPI_BF16) {
        us8 o;
#pragma unroll
        for (int e2 = 0; e2 < 8; ++e2)
          o[e2] = f2b(MODE == EPI_RELU_BF16 ? fmaxf(v[e2], 0.0f) : v[e2]);
        *(us8*)(outb + idx) = o;
      } else {
        *(float4*)(outf + idx) = *(float4*)v;
        *(float4*)(outf + idx + 4) = *(float4*)(v + 4);
      }
    }
  }
}

// ---------------- launch ----------------

extern "C" void kernel_launch(void* const* d_in, const int* in_sizes, int n_in,
                              void* d_out, int out_size, void* d_ws, size_t ws_size,
                              hipStream_t stream) {
  const float* X = (const float*)d_in[0];
  const float* encW0 = (const float*)d_in[1];
  const float* encb0 = (const float*)d_in[2];
  const float* encW1 = (const float*)d_in[3];
  const float* encb1 = (const float*)d_in[4];
  const float* Wne = (const float*)d_in[5];
  const float* bne = (const float*)d_in[6];
  const float* Wen = (const float*)d_in[7];
  const float* ben = (const float*)d_in[8];
  const float* decW0 = (const float*)d_in[9];
  const float* decb0 = (const float*)d_in[10];
  const float* decW1 = (const float*)d_in[11];
  const float* decb1 = (const float*)d_in[12];
  const int* node_idx = (const int*)d_in[13];
  const int* edge_idx = (const int*)d_in[14];
  float* out = (float*)d_out;

  char* p = (char*)d_ws;
  auto alloc = [&](size_t bytes) {
    char* r = p;
    p += (bytes + 255) & ~(size_t)255;
    return r;
  };
  u16* zhi      = (u16*)alloc((size_t)NN * LATD * 2);
  u16* ub       = (u16*)alloc((size_t)NN * LATD * 2);
  u16* h1b      = (u16*)alloc((size_t)NN * LATD * 2);
  u8*  pA       = (u8*)alloc((size_t)NN * LATD);
  u8*  pB       = (u8*)alloc((size_t)NN * LATD);
  u16* Gb       = (u16*)alloc((size_t)NE * LATD * 2);
  u8*  Gf8      = (u8*)alloc((size_t)NE * LATD);
  u16* encW0T   = (u16*)alloc((size_t)OBSD * LATD * 2);
  u16* encW1T   = (u16*)alloc((size_t)LATD * LATD * 2);
  u16* WneB     = (u16*)alloc((size_t)LATD * LATD * 2);
  u16* WenT     = (u16*)alloc((size_t)LATD * LATD * 2);
  u16* WcT      = (u16*)alloc((size_t)LATD * LATD * 2);
  u16* decW0T   = (u16*)alloc((size_t)LATD * LATD * 2);
  u16* decW1T   = (u16*)alloc((size_t)LATD * OBSD * 2);
  float* dvec   = (float*)alloc(LATD * 4);
  float* zeros  = (float*)alloc(LATD * 4);
  int* cnt      = (int*)alloc((size_t)(NE + NN) * 4);
  int* cnt_e = cnt; int* cnt_n = cnt + NE;
  int* off_e    = (int*)alloc((size_t)(NE + 1) * 4);
  int* off_n    = (int*)alloc((size_t)(NN + 1) * 4);
  int* cur_e    = (int*)alloc((size_t)NE * 4);
  int* cur_n    = (int*)alloc((size_t)NN * 4);
  int* lst_e    = (int*)alloc((size_t)NNZC * 4);
  int* lst_n    = (int*)alloc((size_t)NNZC * 4);
  float* recip_e = (float*)alloc((size_t)NE * 4);
  float* recip_n = (float*)alloc((size_t)NN * 4);
  int* bsum_e   = (int*)alloc(16 * 4);
  int* bsum_n   = (int*)alloc(64 * 4);

  size_t needed = (size_t)(p - (char*)d_ws);
  if (needed > ws_size) {
    hipMemsetAsync(d_out, 0x7F, (size_t)out_size * 4, stream);
    return;
  }

  const int nbe = (NE + 1023) / 1024, nbn = (NN + 1023) / 1024;

  // CSR build
  hipMemsetAsync(cnt, 0, (size_t)(NE + NN) * 4, stream);
  count_kernel<<<(NNZC + 255) / 256, 256, 0, stream>>>(node_idx, edge_idx, cnt_n, cnt_e, NNZC);
  scan1_kernel<<<nbe, 1024, 0, stream>>>(cnt_e, off_e, bsum_e, NE);
  scan1_kernel<<<nbn, 1024, 0, stream>>>(cnt_n, off_n, bsum_n, NN);
  scan2_kernel<<<1, 64, 0, stream>>>(bsum_e, nbe);
  scan2_kernel<<<1, 64, 0, stream>>>(bsum_n, nbn);
  scan3_kernel<<<(NE + 255) / 256, 256, 0, stream>>>(cnt_e, off_e, cur_e, recip_e, bsum_e, NE);
  scan3_kernel<<<(NN + 255) / 256, 256, 0, stream>>>(cnt_n, off_n, cur_n, recip_n, bsum_n, NN);
  fill_kernel<<<(NNZC + 255) / 256, 256, 0, stream>>>(node_idx, edge_idx, cur_n, cur_e, lst_n, lst_e, NNZC);

  // weight prep
  transpose_kernel<<<(OBSD * LATD + 255) / 256, 256, 0, stream>>>(encW0, encW0T, OBSD, LATD);
  transpose_kernel<<<(LATD * LATD + 255) / 256, 256, 0, stream>>>(encW1, encW1T, LATD, LATD);
  transpose_kernel<<<(LATD * LATD + 255) / 256, 256, 0, stream>>>(Wen, WenT, LATD, LATD);
  transpose_kernel<<<(LATD * LATD + 255) / 256, 256, 0, stream>>>(decW0, decW0T, LATD, LATD);
  transpose_kernel<<<(LATD * OBSD + 255) / 256, 256, 0, stream>>>(decW1, decW1T, LATD, OBSD);
  to_bf16_kernel<<<(LATD * LATD / 4 + 255) / 256, 256, 0, stream>>>(Wne, WneB, LATD * LATD);
  hipMemsetAsync(zeros, 0, LATD * 4, stream);
  dvec_kernel<<<1, LATD, 0, stream>>>(bne, Wen, ben, dvec);
  gemm_kernel<EPI_BF16><<<dim3(2, 2), 256, 0, stream>>>(WenT, WneB, zeros, LATD, LATD, LATD,
                                                        WcT, nullptr);

  const dim3 blk(256);
  const dim3 g50((NN + 127) / 128, LATD / 128);   // (391, 2)
  const dim3 gdec((NN + 127) / 128, OBSD / 128);  // (391, 1)
  const dim3 geg((NE + 63) / 64);                 // 157 (fused edge gather+GEMM)
  const dim3 gan32((NN + 7) / 8);                 // 6250 (stage 0)
  const dim3 gan16((NN + 15) / 16);               // 3125 (stages 1-3)

  // encode: h1 = relu(X@W0+b0) ; z = h1@W1+b1 -> zhi (bf16)
  to_bf16_kernel<<<(NN * OBSD / 4 + 255) / 256, 256, 0, stream>>>(X, (u16*)pA, NN * OBSD);
  gemm_kernel<EPI_RELU_BF16><<<g50, blk, 0, stream>>>((u16*)pA, encW0T, encb0, NN, LATD, OBSD,
                                                      h1b, nullptr);
  gemm_kernel<EPI_BF16><<<g50, blk, 0, stream>>>(h1b, encW1T, encb1, NN, LATD, LATD,
                                                 zhi, nullptr);

  // RK4: per substep  fused edge gather+GEMM -> fused node-gather+epilogue
  // fp8 k planes ping-pong: k1->pA, k2->pB, k3->pA; stage3 reads k2=pB, k3=pA
  for (int s = 0; s < NSTEPS; ++s) {
    // k=0
    eg_kernel<0><<<geg, blk, 0, stream>>>(zhi, off_e, lst_e, recip_e, WcT, Gb, nullptr);
    aggn_epi_kernel<0><<<gan32, blk, 0, stream>>>(Gb, off_n, lst_n, recip_n, dvec,
                                                  ub, nullptr, nullptr, pA, zhi, 0.f);
    // k=1
    eg_kernel<1><<<geg, blk, 0, stream>>>(pA, off_e, lst_e, recip_e, WcT, nullptr, Gf8);
    aggn_epi_kernel<1><<<gan16, blk, 0, stream>>>(Gf8, off_n, lst_n, recip_n, dvec,
                                                  ub, nullptr, nullptr, pB, zhi, 0.0625f);
    // k=2
    eg_kernel<1><<<geg, blk, 0, stream>>>(pB, off_e, lst_e, recip_e, WcT, nullptr, Gf8);
    aggn_epi_kernel<1><<<gan16, blk, 0, stream>>>(Gf8, off_n, lst_n, recip_n, dvec,
                                                  ub, nullptr, nullptr, pA, zhi, 0.0625f);
    // k=3
    eg_kernel<1><<<geg, blk, 0, stream>>>(pA, off_e, lst_e, recip_e, WcT, nullptr, Gf8);
    aggn_epi_kernel<3><<<gan16, blk, 0, stream>>>(Gf8, off_n, lst_n, recip_n, dvec,
                                                  ub, pB, pA, nullptr, zhi, 0.125f);
  }

  // decode (zhi = bf16(z_final))
  gemm_kernel<EPI_RELU_BF16><<<g50, blk, 0, stream>>>(zhi, decW0T, decb0, NN, LATD, LATD,
                                                      h1b, nullptr);
  gemm_kernel<EPI_F32><<<gdec, blk, 0, stream>>>(h1b, decW1T, decb1, NN, OBSD, LATD,
                                                 nullptr, out);
}

// Round 10
// 1535.242 us; speedup vs baseline: 1.3840x; 1.3840x over previous
//
#include <hip/hip_runtime.h>

#define NN 50000
#define NE 10000
#define NNZC 200000
#define OBSD 128
#define LATD 256
#define NSTEPS 8

typedef unsigned short u16;
typedef unsigned char u8;
typedef __attribute__((ext_vector_type(8))) short bf16x8;
typedef __attribute__((ext_vector_type(4))) float f32x4;
typedef __attribute__((ext_vector_type(2))) float f32x2;
typedef __attribute__((ext_vector_type(4))) u16 us4;
typedef __attribute__((ext_vector_type(8))) u16 us8;
typedef __attribute__((ext_vector_type(16))) u16 us16;
typedef __attribute__((ext_vector_type(2))) unsigned int u32x2;
typedef __attribute__((ext_vector_type(4))) unsigned int u32x4;

__device__ __forceinline__ u16 f2b(float f) {
  unsigned int u = __builtin_bit_cast(unsigned int, f);
  u = (u + 0x7FFFu + ((u >> 16) & 1u)) >> 16;
  return (u16)u;
}
__device__ __forceinline__ float b2f(u16 h) {
  unsigned int u = ((unsigned int)h) << 16;
  return __builtin_bit_cast(float, u);
}
__device__ __forceinline__ float fast_tanh(float x) {
  float e = __expf(2.0f * x);
  return 1.0f - 2.0f / (e + 1.0f);
}

// ---- OCP e4m3 fp8 pack/unpack (HW converts, gfx950) ----
__device__ __forceinline__ void fp8_dec4(unsigned int w, float* o) {
  f32x2 a = __builtin_amdgcn_cvt_pk_f32_fp8((int)w, false);
  f32x2 b = __builtin_amdgcn_cvt_pk_f32_fp8((int)w, true);
  o[0] = a[0]; o[1] = a[1]; o[2] = b[0]; o[3] = b[1];
}
__device__ __forceinline__ void fp8_dec16(u32x4 w, float* o) {
#pragma unroll
  for (int q = 0; q < 4; ++q) fp8_dec4(w[q], o + q * 4);
}
__device__ __forceinline__ unsigned int fp8_enc4(const float* v) {
  int lo = __builtin_amdgcn_cvt_pk_fp8_f32(v[0], v[1], 0, false);
  lo = __builtin_amdgcn_cvt_pk_fp8_f32(v[2], v[3], lo, true);
  return (unsigned int)lo;
}

typedef __attribute__((address_space(1))) const unsigned int GU32;
typedef __attribute__((address_space(3))) unsigned int LU32;
__device__ __forceinline__ void async16(const void* g, void* l) {
  __builtin_amdgcn_global_load_lds((GU32*)g, (LU32*)l, 16, 0, 0);
}

// ---------------- CSR build ----------------

__global__ void count_kernel(const int* __restrict__ ni, const int* __restrict__ ei,
                             int* __restrict__ cnt_n, int* __restrict__ cnt_e, int nnz) {
  int i = blockIdx.x * blockDim.x + threadIdx.x;
  if (i < nnz) {
    atomicAdd(&cnt_n[ni[i]], 1);
    atomicAdd(&cnt_e[ei[i]], 1);
  }
}

__global__ __launch_bounds__(1024) void scan1_kernel(const int* __restrict__ cnt,
                                                     int* __restrict__ off,
                                                     int* __restrict__ bsum, int n) {
  __shared__ int ws[16];
  const int tid = threadIdx.x;
  const int lane = tid & 63, w = tid >> 6;
  const int i = blockIdx.x * 1024 + tid;
  int v = (i < n) ? cnt[i] : 0;
  int s = v;
#pragma unroll
  for (int d = 1; d < 64; d <<= 1) {
    int t2 = __shfl_up(s, d);
    if (lane >= d) s += t2;
  }
  if (lane == 63) ws[w] = s;
  __syncthreads();
  if (w == 0) {
    int x = (lane < 16) ? ws[lane] : 0;
#pragma unroll
    for (int d = 1; d < 16; d <<= 1) {
      int t2 = __shfl_up(x, d);
      if (lane >= d) x += t2;
    }
    if (lane < 16) ws[lane] = x;
  }
  __syncthreads();
  const int base = w ? ws[w - 1] : 0;
  if (i < n) off[i] = base + s - v;
  if (tid == 0) bsum[blockIdx.x] = ws[15];
}

__global__ void scan2_kernel(int* __restrict__ bsum, int nb) {
  const int lane = threadIdx.x;
  int v = (lane < nb) ? bsum[lane] : 0;
  int s = v;
#pragma unroll
  for (int d = 1; d < 64; d <<= 1) {
    int t2 = __shfl_up(s, d);
    if (lane >= d) s += t2;
  }
  if (lane < nb) bsum[lane] = s - v;
  if (lane == 63) bsum[nb] = s;
}

__global__ void scan3_kernel(const int* __restrict__ cnt, int* __restrict__ off,
                             int* __restrict__ cur, float* __restrict__ recip,
                             const int* __restrict__ bsum, int n) {
  const int i = blockIdx.x * blockDim.x + threadIdx.x;
  if (i < n) {
    const int o = off[i] + bsum[i >> 10];
    off[i] = o;
    cur[i] = o;
    recip[i] = 1.0f / fmaxf((float)cnt[i], 1.0f);
  }
  if (i == 0) off[n] = bsum[(n + 1023) >> 10];
}

__global__ void fill_kernel(const int* __restrict__ ni, const int* __restrict__ ei,
                            int* __restrict__ cur_n, int* __restrict__ cur_e,
                            int* __restrict__ lst_n, int* __restrict__ lst_e, int nnz) {
  int i = blockIdx.x * blockDim.x + threadIdx.x;
  if (i < nnz) {
    int n = ni[i], e = ei[i];
    lst_e[atomicAdd(&cur_e[e], 1)] = n;
    lst_n[atomicAdd(&cur_n[n], 1)] = e;
  }
}

// ---------------- small prep ----------------

__global__ void transpose_kernel(const float* __restrict__ W, u16* __restrict__ WT, int K, int N) {
  int i = blockIdx.x * blockDim.x + threadIdx.x;
  if (i >= K * N) return;
  int k = i / N, n = i - k * N;
  WT[n * K + k] = f2b(W[i]);
}

__global__ void to_bf16_kernel(const float* __restrict__ src, u16* __restrict__ dst, int n) {
  int i = (blockIdx.x * blockDim.x + threadIdx.x) * 4;
  if (i >= n) return;
  float4 v = *reinterpret_cast<const float4*>(src + i);
  us4 o;
  o.x = f2b(v.x); o.y = f2b(v.y); o.z = f2b(v.z); o.w = f2b(v.w);
  *reinterpret_cast<us4*>(dst + i) = o;
}

// d = bne @ Wen + ben
__global__ void dvec_kernel(const float* __restrict__ bne, const float* __restrict__ Wen,
                            const float* __restrict__ ben, float* __restrict__ d) {
  const int j = threadIdx.x;
  float s = ben[j];
  for (int k = 0; k < LATD; ++k) s += bne[k] * Wen[k * LATD + j];
  d[j] = s;
}

// ---------------- edge segment mean (4-deep pipelined gather) ----------------

template <int FP8SRC>
__global__ __launch_bounds__(256) void agg_kernel(const void* __restrict__ src,
                                                  const int* __restrict__ off,
                                                  const int* __restrict__ lst,
                                                  const float* __restrict__ recip,
                                                  u16* __restrict__ dst, int nseg) {
  constexpr int GW = FP8SRC ? 16 : 32;
  constexpr int EPL = LATD / GW;  // 16 or 8
  const int t = threadIdx.x;
  const int gl = t & (GW - 1);
  const int seg = blockIdx.x * (256 / GW) + (t / GW);
  if (seg >= nseg) return;
  const int s = off[seg], e = off[seg + 1];
  float a[EPL] = {};
  int p = s;
  if constexpr (FP8SRC) {
    for (; p + 4 <= e; p += 4) {
      const int r0 = lst[p], r1 = lst[p + 1], r2 = lst[p + 2], r3 = lst[p + 3];
      const u32x4 w0 = *(const u32x4*)((const u8*)src + (size_t)r0 * LATD + gl * 16);
      const u32x4 w1 = *(const u32x4*)((const u8*)src + (size_t)r1 * LATD + gl * 16);
      const u32x4 w2 = *(const u32x4*)((const u8*)src + (size_t)r2 * LATD + gl * 16);
      const u32x4 w3 = *(const u32x4*)((const u8*)src + (size_t)r3 * LATD + gl * 16);
      float f[16];
      fp8_dec16(w0, f);
#pragma unroll
      for (int j = 0; j < 16; ++j) a[j] += f[j];
      fp8_dec16(w1, f);
#pragma unroll
      for (int j = 0; j < 16; ++j) a[j] += f[j];
      fp8_dec16(w2, f);
#pragma unroll
      for (int j = 0; j < 16; ++j) a[j] += f[j];
      fp8_dec16(w3, f);
#pragma unroll
      for (int j = 0; j < 16; ++j) a[j] += f[j];
    }
    for (; p < e; ++p) {
      const u32x4 w = *(const u32x4*)((const u8*)src + (size_t)lst[p] * LATD + gl * 16);
      float f[16];
      fp8_dec16(w, f);
#pragma unroll
      for (int j = 0; j < 16; ++j) a[j] += f[j];
    }
  } else {
    for (; p + 4 <= e; p += 4) {
      const int r0 = lst[p], r1 = lst[p + 1], r2 = lst[p + 2], r3 = lst[p + 3];
      const us8 v0 = *(const us8*)((const u16*)src + (size_t)r0 * LATD + gl * 8);
      const us8 v1 = *(const us8*)((const u16*)src + (size_t)r1 * LATD + gl * 8);
      const us8 v2 = *(const us8*)((const u16*)src + (size_t)r2 * LATD + gl * 8);
      const us8 v3 = *(const us8*)((const u16*)src + (size_t)r3 * LATD + gl * 8);
#pragma unroll
      for (int j = 0; j < 8; ++j)
        a[j] += b2f(v0[j]) + b2f(v1[j]) + b2f(v2[j]) + b2f(v3[j]);
    }
    for (; p < e; ++p) {
      const us8 v = *(const us8*)((const u16*)src + (size_t)lst[p] * LATD + gl * 8);
#pragma unroll
      for (int j = 0; j < 8; ++j) a[j] += b2f(v[j]);
    }
  }
  const float rc = recip[seg];
  const size_t base = (size_t)seg * LATD + gl * EPL;
  if constexpr (FP8SRC) {
    us16 o;
#pragma unroll
    for (int j = 0; j < 16; ++j) o[j] = f2b(a[j] * rc);
    *(us16*)(dst + base) = o;
  } else {
    us8 o;
#pragma unroll
    for (int j = 0; j < 8; ++j) o[j] = f2b(a[j] * rc);
    *(us8*)(dst + base) = o;
  }
}

// ---------------- fused node-gather + RK epilogue ----------------

template <int STAGE>
__global__ __launch_bounds__(256) void aggn_epi_kernel(
    const void* __restrict__ G, const int* __restrict__ off, const int* __restrict__ lst,
    const float* __restrict__ recip, const float* __restrict__ dvec,
    u16* __restrict__ ub, const u8* __restrict__ k2s, const u8* __restrict__ k3s,
    u8* __restrict__ kout8, u16* __restrict__ zhi, float c) {
  constexpr int GW = (STAGE == 0) ? 32 : 16;
  constexpr int EPL = LATD / GW;  // 8 or 16
  const int t = threadIdx.x;
  const int gl = t & (GW - 1);
  const int node = blockIdx.x * (256 / GW) + (t / GW);
  if (node >= NN) return;
  const int s = off[node], e = off[node + 1];
  float v[EPL] = {};
  int p = s;
  if constexpr (STAGE == 0) {
    for (; p + 2 <= e; p += 2) {
      const int r0 = lst[p], r1 = lst[p + 1];
      const us8 g0 = *(const us8*)((const u16*)G + (size_t)r0 * LATD + gl * 8);
      const us8 g1 = *(const us8*)((const u16*)G + (size_t)r1 * LATD + gl * 8);
#pragma unroll
      for (int j = 0; j < 8; ++j) v[j] += b2f(g0[j]) + b2f(g1[j]);
    }
    for (; p < e; ++p) {
      const us8 g = *(const us8*)((const u16*)G + (size_t)lst[p] * LATD + gl * 8);
#pragma unroll
      for (int j = 0; j < 8; ++j) v[j] += b2f(g[j]);
    }
  } else {
    for (; p + 2 <= e; p += 2) {
      const int r0 = lst[p], r1 = lst[p + 1];
      const u32x4 w0 = *(const u32x4*)((const u8*)G + (size_t)r0 * LATD + gl * 16);
      const u32x4 w1 = *(const u32x4*)((const u8*)G + (size_t)r1 * LATD + gl * 16);
      float f[16];
      fp8_dec16(w0, f);
#pragma unroll
      for (int j = 0; j < 16; ++j) v[j] += f[j];
      fp8_dec16(w1, f);
#pragma unroll
      for (int j = 0; j < 16; ++j) v[j] += f[j];
    }
    for (; p < e; ++p) {
      const u32x4 w = *(const u32x4*)((const u8*)G + (size_t)lst[p] * LATD + gl * 16);
      float f[16];
      fp8_dec16(w, f);
#pragma unroll
      for (int j = 0; j < 16; ++j) v[j] += f[j];
    }
  }
  const float rc = recip[node];
  const size_t base = (size_t)node * LATD + gl * EPL;
  const float dt6 = 0.125f / 6.0f;

  if constexpr (STAGE == 0) {
    float kv[8];
    us8 uo;
#pragma unroll
    for (int j = 0; j < 8; ++j) {
      const float u = v[j] * rc + dvec[gl * 8 + j];
      uo[j] = f2b(u);
      kv[j] = fast_tanh(u);
    }
    *(us8*)(ub + base) = uo;
    u32x2 kp;
    kp[0] = fp8_enc4(kv);
    kp[1] = fp8_enc4(kv + 4);
    *(u32x2*)(kout8 + base) = kp;
  } else if constexpr (STAGE == 1) {
    const us16 uv = *(const us16*)(ub + base);
    float kv[16];
#pragma unroll
    for (int j = 0; j < 16; ++j)
      kv[j] = fast_tanh(b2f(uv[j]) + c * (v[j] * rc));
    u32x4 kp;
#pragma unroll
    for (int q = 0; q < 4; ++q) kp[q] = fp8_enc4(kv + q * 4);
    *(u32x4*)(kout8 + base) = kp;
  } else {  // STAGE 3
    const us16 uv = *(const us16*)(ub + base);
    const u32x4 w2 = *(const u32x4*)(k2s + base);
    const u32x4 w3 = *(const u32x4*)(k3s + base);
    const us16 zh = *(const us16*)(zhi + base);
    float f2[16], f3[16];
    fp8_dec16(w2, f2);
    fp8_dec16(w3, f3);
    us16 ho;
#pragma unroll
    for (int j = 0; j < 16; ++j) {
      const float u = b2f(uv[j]);
      const float k1 = fast_tanh(u);
      const float k4 = fast_tanh(u + c * (v[j] * rc));
      const float zn = b2f(zh[j]) + dt6 * (k1 + 2.0f * f2[j] + 2.0f * f3[j] + k4);
      ho[j] = f2b(zn);
    }
    *(us16*)(zhi + base) = ho;
  }
}

// ---------------- 64x128-tile edge GEMM: G = A[NE x 256] @ WcT^T, no bias ----------------
// Grid (157, 2), 314 blocks -> better latency hiding for the small M.
// Wave w covers 64 rows x 32 cols (acc[4][2]). OUT=0: bf16 Gb; OUT=1: fp8 Gf8.

template <int OUT8>
__global__ __launch_bounds__(256) void gemm64_kernel(
    const u16* __restrict__ A, const u16* __restrict__ BT,
    u16* __restrict__ Gb, u8* __restrict__ Gf8) {
  __shared__ char smem[4 * 16 * 66 * 4];  // 16896B; GEMM uses first 12KB
  u16* lA = (u16*)smem;                   // 64 x 32 = 4KB
  u16* lB = (u16*)(smem + 4096);          // 128 x 32 = 8KB
  const int t = threadIdx.x;
  const int m0 = blockIdx.x * 64, n0 = blockIdx.y * 128;
  const int srow = t >> 2;
  const int gslot = (t & 3) ^ ((srow >> 1) & 3);

  int ar = m0 + srow; if (ar > NE - 1) ar = NE - 1;
  const u16* gA = A + (size_t)ar * LATD + gslot * 8;
  const u16* gB0 = BT + (size_t)(n0 + srow) * LATD + gslot * 8;
  const u16* gB1 = BT + (size_t)(n0 + 64 + srow) * LATD + gslot * 8;
  char* lAd = (char*)lA + t * 16;
  char* lBd0 = (char*)lB + t * 16;
  char* lBd1 = lBd0 + 4096;

  const int lane = t & 63, wid = t >> 6;
  const int lrow = lane & 15, kg = lane >> 4;

  f32x4 acc[4][2] = {};
  const char* lAb = (const char*)lA;
  const char* lBb = (const char*)lB;

  for (int c = 0; c < 8; ++c) {
    const int kk = c * 32;
    async16(gA + kk, lAd);
    async16(gB0 + kk, lBd0);
    async16(gB1 + kk, lBd1);
    __syncthreads();
    bf16x8 af[4], bg[2];
#pragma unroll
    for (int i = 0; i < 4; ++i) {
      const int rA = i * 16 + lrow;
      af[i] = *(const bf16x8*)(lAb + rA * 64 + (((kg ^ (rA >> 1)) & 3) << 4));
    }
#pragma unroll
    for (int j = 0; j < 2; ++j) {
      const int rB = wid * 32 + j * 16 + lrow;
      bg[j] = *(const bf16x8*)(lBb + rB * 64 + (((kg ^ (rB >> 1)) & 3) << 4));
    }
#pragma unroll
    for (int i = 0; i < 4; ++i)
#pragma unroll
      for (int j = 0; j < 2; ++j)
        acc[i][j] = __builtin_amdgcn_mfma_f32_16x16x32_bf16(af[i], bg[j], acc[i][j], 0, 0, 0);
    __syncthreads();
  }

  // staged epilogue: wave-private 16x66 f32 region; 16 rows x 4 col-octets = 64 lanes
  float* stage = (float*)smem + wid * (16 * 66);
  const int rr = lane >> 2;
  const int c0 = (lane & 3) * 8;

#pragma unroll
  for (int ti = 0; ti < 4; ++ti) {
#pragma unroll
    for (int tj = 0; tj < 2; ++tj)
#pragma unroll
      for (int j = 0; j < 4; ++j)
        stage[(kg * 4 + j) * 66 + tj * 16 + lrow] = acc[ti][tj][j];
    const int gr = m0 + ti * 16 + rr;
    if (gr < NE) {
      const int gc = n0 + wid * 32 + c0;
      const size_t idx = (size_t)gr * LATD + gc;
      float v[8];
      *(float4*)v = *(const float4*)&stage[rr * 66 + c0];
      *(float4*)(v + 4) = *(const float4*)&stage[rr * 66 + c0 + 4];
      if constexpr (OUT8) {
        u32x2 kp;
        kp[0] = fp8_enc4(v);
        kp[1] = fp8_enc4(v + 4);
        *(u32x2*)(Gf8 + idx) = kp;
      } else {
        us8 o;
#pragma unroll
        for (int e2 = 0; e2 < 8; ++e2) o[e2] = f2b(v[e2]);
        *(us8*)(Gb + idx) = o;
      }
    }
  }
}

// ---------------- 128-tile MFMA GEMM (enc/dec/prep) ----------------

enum { EPI_RELU_BF16, EPI_BF16, EPI_F32 };

template <int MODE>
__global__ __launch_bounds__(256) void gemm_kernel(
    const u16* __restrict__ A, const u16* __restrict__ BT, const float* __restrict__ bias,
    int M, int N, int K,
    u16* __restrict__ outb, float* __restrict__ outf) {
  __shared__ char smem[4 * 16 * 66 * 4];
  u16* lA = (u16*)smem;
  u16* lB = (u16*)(smem + 8192);
  const int t = threadIdx.x;
  const int m0 = blockIdx.x * 128, n0 = blockIdx.y * 128;
  const int srow = t >> 2;
  const int gslot = (t & 3) ^ ((srow >> 1) & 3);

  int ar0 = m0 + srow;      if (ar0 > M - 1) ar0 = M - 1;
  int ar1 = m0 + srow + 64; if (ar1 > M - 1) ar1 = M - 1;
  const u16* gA0 = A + (size_t)ar0 * K + gslot * 8;
  const u16* gA1 = A + (size_t)ar1 * K + gslot * 8;
  const u16* gB0 = BT + (size_t)(n0 + srow) * K + gslot * 8;
  const u16* gB1 = BT + (size_t)(n0 + srow + 64) * K + gslot * 8;
  char* lAd0 = (char*)lA + t * 16; char* lAd1 = lAd0 + 4096;
  char* lBd0 = (char*)lB + t * 16; char* lBd1 = lBd0 + 4096;

  const int lane = t & 63, wid = t >> 6;
  const int wm = wid >> 1, wn = wid & 1;
  const int lrow = lane & 15, kg = lane >> 4;

  f32x4 acc[4][4] = {};
  const char* lAb = (const char*)lA;
  const char* lBb = (const char*)lB;

  for (int kk = 0; kk < K; kk += 32) {
    async16(gA0 + kk, lAd0);
    async16(gA1 + kk, lAd1);
    async16(gB0 + kk, lBd0);
    async16(gB1 + kk, lBd1);
    __syncthreads();
    bf16x8 af[4], bg[4];
#pragma unroll
    for (int i = 0; i < 4; ++i) {
      int rA = wm * 64 + i * 16 + lrow;
      af[i] = *(const bf16x8*)(lAb + rA * 64 + (((kg ^ (rA >> 1)) & 3) << 4));
      int rB = wn * 64 + i * 16 + lrow;
      bg[i] = *(const bf16x8*)(lBb + rB * 64 + (((kg ^ (rB >> 1)) & 3) << 4));
    }
#pragma unroll
    for (int i = 0; i < 4; ++i)
#pragma unroll
      for (int j = 0; j < 4; ++j)
        acc[i][j] = __builtin_amdgcn_mfma_f32_16x16x32_bf16(af[i], bg[j], acc[i][j], 0, 0, 0);
    __syncthreads();
  }

  float* stage = (float*)smem + wid * (16 * 66);
  const int rr = lane >> 3;
  const int c0 = (lane & 7) * 8;

#pragma unroll
  for (int ti = 0; ti < 4; ++ti) {
#pragma unroll
    for (int tj = 0; tj < 4; ++tj) {
      const float bv = bias[n0 + wn * 64 + tj * 16 + lrow];
#pragma unroll
      for (int j = 0; j < 4; ++j)
        stage[(kg * 4 + j) * 66 + tj * 16 + lrow] = acc[ti][tj][j] + bv;
    }
#pragma unroll
    for (int pass = 0; pass < 2; ++pass) {
      const int r = pass * 8 + rr;
      const int gr = m0 + wm * 64 + ti * 16 + r;
      if (gr >= M) continue;
      const int gc = n0 + wn * 64 + c0;
      const size_t idx = (size_t)gr * N + gc;
      float v[8];
      *(float4*)v = *(const float4*)&stage[r * 66 + c0];
      *(float4*)(v + 4) = *(const float4*)&stage[r * 66 + c0 + 4];

      if constexpr (MODE == EPI_RELU_BF16 || MODE == EPI_BF16) {
        us8 o;
#pragma unroll
        for (int e2 = 0; e2 < 8; ++e2)
          o[e2] = f2b(MODE == EPI_RELU_BF16 ? fmaxf(v[e2], 0.0f) : v[e2]);
        *(us8*)(outb + idx) = o;
      } else {
        *(float4*)(outf + idx) = *(float4*)v;
        *(float4*)(outf + idx + 4) = *(float4*)(v + 4);
      }
    }
  }
}

// ---------------- launch ----------------

extern "C" void kernel_launch(void* const* d_in, const int* in_sizes, int n_in,
                              void* d_out, int out_size, void* d_ws, size_t ws_size,
                              hipStream_t stream) {
  const float* X = (const float*)d_in[0];
  const float* encW0 = (const float*)d_in[1];
  const float* encb0 = (const float*)d_in[2];
  const float* encW1 = (const float*)d_in[3];
  const float* encb1 = (const float*)d_in[4];
  const float* Wne = (const float*)d_in[5];
  const float* bne = (const float*)d_in[6];
  const float* Wen = (const float*)d_in[7];
  const float* ben = (const float*)d_in[8];
  const float* decW0 = (const float*)d_in[9];
  const float* decb0 = (const float*)d_in[10];
  const float* decW1 = (const float*)d_in[11];
  const float* decb1 = (const float*)d_in[12];
  const int* node_idx = (const int*)d_in[13];
  const int* edge_idx = (const int*)d_in[14];
  float* out = (float*)d_out;

  char* p = (char*)d_ws;
  auto alloc = [&](size_t bytes) {
    char* r = p;
    p += (bytes + 255) & ~(size_t)255;
    return r;
  };
  u16* zhi      = (u16*)alloc((size_t)NN * LATD * 2);
  u16* ub       = (u16*)alloc((size_t)NN * LATD * 2);
  u16* h1b      = (u16*)alloc((size_t)NN * LATD * 2);
  u8*  pA       = (u8*)alloc((size_t)NN * LATD);
  u8*  pB       = (u8*)alloc((size_t)NN * LATD);
  u16* eagg     = (u16*)alloc((size_t)NE * LATD * 2);
  u16* Gb       = (u16*)alloc((size_t)NE * LATD * 2);
  u8*  Gf8      = (u8*)alloc((size_t)NE * LATD);
  u16* encW0T   = (u16*)alloc((size_t)OBSD * LATD * 2);
  u16* encW1T   = (u16*)alloc((size_t)LATD * LATD * 2);
  u16* WneB     = (u16*)alloc((size_t)LATD * LATD * 2);
  u16* WenT     = (u16*)alloc((size_t)LATD * LATD * 2);
  u16* WcT      = (u16*)alloc((size_t)LATD * LATD * 2);
  u16* decW0T   = (u16*)alloc((size_t)LATD * LATD * 2);
  u16* decW1T   = (u16*)alloc((size_t)LATD * OBSD * 2);
  float* dvec   = (float*)alloc(LATD * 4);
  float* zeros  = (float*)alloc(LATD * 4);
  int* cnt      = (int*)alloc((size_t)(NE + NN) * 4);
  int* cnt_e = cnt; int* cnt_n = cnt + NE;
  int* off_e    = (int*)alloc((size_t)(NE + 1) * 4);
  int* off_n    = (int*)alloc((size_t)(NN + 1) * 4);
  int* cur_e    = (int*)alloc((size_t)NE * 4);
  int* cur_n    = (int*)alloc((size_t)NN * 4);
  int* lst_e    = (int*)alloc((size_t)NNZC * 4);
  int* lst_n    = (int*)alloc((size_t)NNZC * 4);
  float* recip_e = (float*)alloc((size_t)NE * 4);
  float* recip_n = (float*)alloc((size_t)NN * 4);
  int* bsum_e   = (int*)alloc(16 * 4);
  int* bsum_n   = (int*)alloc(64 * 4);

  size_t needed = (size_t)(p - (char*)d_ws);
  if (needed > ws_size) {
    hipMemsetAsync(d_out, 0x7F, (size_t)out_size * 4, stream);
    return;
  }

  const int nbe = (NE + 1023) / 1024, nbn = (NN + 1023) / 1024;

  // CSR build
  hipMemsetAsync(cnt, 0, (size_t)(NE + NN) * 4, stream);
  count_kernel<<<(NNZC + 255) / 256, 256, 0, stream>>>(node_idx, edge_idx, cnt_n, cnt_e, NNZC);
  scan1_kernel<<<nbe, 1024, 0, stream>>>(cnt_e, off_e, bsum_e, NE);
  scan1_kernel<<<nbn, 1024, 0, stream>>>(cnt_n, off_n, bsum_n, NN);
  scan2_kernel<<<1, 64, 0, stream>>>(bsum_e, nbe);
  scan2_kernel<<<1, 64, 0, stream>>>(bsum_n, nbn);
  scan3_kernel<<<(NE + 255) / 256, 256, 0, stream>>>(cnt_e, off_e, cur_e, recip_e, bsum_e, NE);
  scan3_kernel<<<(NN + 255) / 256, 256, 0, stream>>>(cnt_n, off_n, cur_n, recip_n, bsum_n, NN);
  fill_kernel<<<(NNZC + 255) / 256, 256, 0, stream>>>(node_idx, edge_idx, cur_n, cur_e, lst_n, lst_e, NNZC);

  // weight prep
  transpose_kernel<<<(OBSD * LATD + 255) / 256, 256, 0, stream>>>(encW0, encW0T, OBSD, LATD);
  transpose_kernel<<<(LATD * LATD + 255) / 256, 256, 0, stream>>>(encW1, encW1T, LATD, LATD);
  transpose_kernel<<<(LATD * LATD + 255) / 256, 256, 0, stream>>>(Wen, WenT, LATD, LATD);
  transpose_kernel<<<(LATD * LATD + 255) / 256, 256, 0, stream>>>(decW0, decW0T, LATD, LATD);
  transpose_kernel<<<(LATD * OBSD + 255) / 256, 256, 0, stream>>>(decW1, decW1T, LATD, OBSD);
  to_bf16_kernel<<<(LATD * LATD / 4 + 255) / 256, 256, 0, stream>>>(Wne, WneB, LATD * LATD);
  hipMemsetAsync(zeros, 0, LATD * 4, stream);
  dvec_kernel<<<1, LATD, 0, stream>>>(bne, Wen, ben, dvec);
  gemm_kernel<EPI_BF16><<<dim3(2, 2), 256, 0, stream>>>(WenT, WneB, zeros, LATD, LATD, LATD,
                                                        WcT, nullptr);

  const dim3 blk(256);
  const dim3 g50((NN + 127) / 128, LATD / 128);   // (391, 2)
  const dim3 gdec((NN + 127) / 128, OBSD / 128);  // (391, 1)
  const dim3 g64((NE + 63) / 64, 2);              // (157, 2) = 314 blocks (edge GEMM)
  const dim3 gae32((NE + 7) / 8);                 // 1250 (bf16 src)
  const dim3 gae16((NE + 15) / 16);               // 625  (fp8 src)
  const dim3 gan32((NN + 7) / 8);                 // 6250 (stage 0)
  const dim3 gan16((NN + 15) / 16);               // 3125 (stages 1-3)

  // encode: h1 = relu(X@W0+b0) ; z = h1@W1+b1 -> zhi (bf16)
  to_bf16_kernel<<<(NN * OBSD / 4 + 255) / 256, 256, 0, stream>>>(X, (u16*)pA, NN * OBSD);
  gemm_kernel<EPI_RELU_BF16><<<g50, blk, 0, stream>>>((u16*)pA, encW0T, encb0, NN, LATD, OBSD,
                                                      h1b, nullptr);
  gemm_kernel<EPI_BF16><<<g50, blk, 0, stream>>>(h1b, encW1T, encb1, NN, LATD, LATD,
                                                 zhi, nullptr);

  // RK4: per substep  agg_e -> edge GEMM (64-tile) -> fused node-gather+epilogue
  // fp8 k planes ping-pong: k1->pA, k2->pB, k3->pA; stage3 reads k2=pB, k3=pA
  for (int s = 0; s < NSTEPS; ++s) {
    // k=0
    agg_kernel<0><<<gae32, blk, 0, stream>>>(zhi, off_e, lst_e, recip_e, eagg, NE);
    gemm64_kernel<0><<<g64, blk, 0, stream>>>(eagg, WcT, Gb, nullptr);
    aggn_epi_kernel<0><<<gan32, blk, 0, stream>>>(Gb, off_n, lst_n, recip_n, dvec,
                                                  ub, nullptr, nullptr, pA, zhi, 0.f);
    // k=1
    agg_kernel<1><<<gae16, blk, 0, stream>>>(pA, off_e, lst_e, recip_e, eagg, NE);
    gemm64_kernel<1><<<g64, blk, 0, stream>>>(eagg, WcT, nullptr, Gf8);
    aggn_epi_kernel<1><<<gan16, blk, 0, stream>>>(Gf8, off_n, lst_n, recip_n, dvec,
                                                  ub, nullptr, nullptr, pB, zhi, 0.0625f);
    // k=2
    agg_kernel<1><<<gae16, blk, 0, stream>>>(pB, off_e, lst_e, recip_e, eagg, NE);
    gemm64_kernel<1><<<g64, blk, 0, stream>>>(eagg, WcT, nullptr, Gf8);
    aggn_epi_kernel<1><<<gan16, blk, 0, stream>>>(Gf8, off_n, lst_n, recip_n, dvec,
                                                  ub, nullptr, nullptr, pA, zhi, 0.0625f);
    // k=3
    agg_kernel<1><<<gae16, blk, 0, stream>>>(pA, off_e, lst_e, recip_e, eagg, NE);
    gemm64_kernel<1><<<g64, blk, 0, stream>>>(eagg, WcT, nullptr, Gf8);
    aggn_epi_kernel<3><<<gan16, blk, 0, stream>>>(Gf8, off_n, lst_n, recip_n, dvec,
                                                  ub, pB, pA, nullptr, zhi, 0.125f);
  }

  // decode (zhi = bf16(z_final))
  gemm_kernel<EPI_RELU_BF16><<<g50, blk, 0, stream>>>(zhi, decW0T, decb0, NN, LATD, LATD,
                                                      h1b, nullptr);
  gemm_kernel<EPI_F32><<<gdec, blk, 0, stream>>>(h1b, decW1T, decb1, NN, OBSD, LATD,
                                                 nullptr, out);
}

// Round 11
// 1525.215 us; speedup vs baseline: 1.3931x; 1.0066x over previous
//
#include <hip/hip_runtime.h>

#define NN 50000
#define NE 10000
#define NNZC 200000
#define OBSD 128
#define LATD 256
#define NSTEPS 8

typedef unsigned short u16;
typedef unsigned char u8;
typedef __attribute__((ext_vector_type(8))) short bf16x8;
typedef __attribute__((ext_vector_type(4))) float f32x4;
typedef __attribute__((ext_vector_type(2))) float f32x2;
typedef __attribute__((ext_vector_type(4))) u16 us4;
typedef __attribute__((ext_vector_type(8))) u16 us8;
typedef __attribute__((ext_vector_type(16))) u16 us16;
typedef __attribute__((ext_vector_type(2))) unsigned int u32x2;
typedef __attribute__((ext_vector_type(4))) unsigned int u32x4;

__device__ __forceinline__ u16 f2b(float f) {
  unsigned int u = __builtin_bit_cast(unsigned int, f);
  u = (u + 0x7FFFu + ((u >> 16) & 1u)) >> 16;
  return (u16)u;
}
__device__ __forceinline__ float b2f(u16 h) {
  unsigned int u = ((unsigned int)h) << 16;
  return __builtin_bit_cast(float, u);
}
__device__ __forceinline__ float fast_tanh(float x) {
  float e = __expf(2.0f * x);
  return 1.0f - 2.0f / (e + 1.0f);
}

// ---- OCP e4m3 fp8 pack/unpack (HW converts, gfx950) ----
__device__ __forceinline__ void fp8_dec4(unsigned int w, float* o) {
  f32x2 a = __builtin_amdgcn_cvt_pk_f32_fp8((int)w, false);
  f32x2 b = __builtin_amdgcn_cvt_pk_f32_fp8((int)w, true);
  o[0] = a[0]; o[1] = a[1]; o[2] = b[0]; o[3] = b[1];
}
__device__ __forceinline__ void fp8_dec16(u32x4 w, float* o) {
#pragma unroll
  for (int q = 0; q < 4; ++q) fp8_dec4(w[q], o + q * 4);
}
__device__ __forceinline__ unsigned int fp8_enc4(const float* v) {
  int lo = __builtin_amdgcn_cvt_pk_fp8_f32(v[0], v[1], 0, false);
  lo = __builtin_amdgcn_cvt_pk_fp8_f32(v[2], v[3], lo, true);
  return (unsigned int)lo;
}

typedef __attribute__((address_space(1))) const unsigned int GU32;
typedef __attribute__((address_space(3))) unsigned int LU32;
__device__ __forceinline__ void async16(const void* g, void* l) {
  __builtin_amdgcn_global_load_lds((GU32*)g, (LU32*)l, 16, 0, 0);
}

// ---------------- CSR build ----------------

__global__ void count_kernel(const int* __restrict__ ni, const int* __restrict__ ei,
                             int* __restrict__ cnt_n, int* __restrict__ cnt_e, int nnz) {
  int i = blockIdx.x * blockDim.x + threadIdx.x;
  if (i < nnz) {
    atomicAdd(&cnt_n[ni[i]], 1);
    atomicAdd(&cnt_e[ei[i]], 1);
  }
}

// merged scan phase 1: blocks [0,nbe) handle edges, [nbe, nbe+nbn) nodes
__global__ __launch_bounds__(1024) void scan1_kernel(
    const int* __restrict__ cnt_e, int* __restrict__ off_e, int* __restrict__ bsum_e, int ne, int nbe,
    const int* __restrict__ cnt_n, int* __restrict__ off_n, int* __restrict__ bsum_n, int nn) {
  __shared__ int ws[16];
  const int b = blockIdx.x;
  const int* cnt; int* off; int* bsum; int n, bi;
  if (b < nbe) { cnt = cnt_e; off = off_e; bsum = bsum_e; n = ne; bi = b; }
  else         { cnt = cnt_n; off = off_n; bsum = bsum_n; n = nn; bi = b - nbe; }
  const int tid = threadIdx.x;
  const int lane = tid & 63, w = tid >> 6;
  const int i = bi * 1024 + tid;
  int v = (i < n) ? cnt[i] : 0;
  int s = v;
#pragma unroll
  for (int d = 1; d < 64; d <<= 1) {
    int t2 = __shfl_up(s, d);
    if (lane >= d) s += t2;
  }
  if (lane == 63) ws[w] = s;
  __syncthreads();
  if (w == 0) {
    int x = (lane < 16) ? ws[lane] : 0;
#pragma unroll
    for (int d = 1; d < 16; d <<= 1) {
      int t2 = __shfl_up(x, d);
      if (lane >= d) x += t2;
    }
    if (lane < 16) ws[lane] = x;
  }
  __syncthreads();
  const int base = w ? ws[w - 1] : 0;
  if (i < n) off[i] = base + s - v;
  if (tid == 0) bsum[bi] = ws[15];
}

// merged scan phase 2: wave 0 -> edges, wave 1 -> nodes
__global__ void scan2_kernel(int* __restrict__ bsum_e, int nbe,
                             int* __restrict__ bsum_n, int nbn) {
  int* bsum = (threadIdx.x < 64) ? bsum_e : bsum_n;
  const int nb = (threadIdx.x < 64) ? nbe : nbn;
  const int lane = threadIdx.x & 63;
  int v = (lane < nb) ? bsum[lane] : 0;
  int s = v;
#pragma unroll
  for (int d = 1; d < 64; d <<= 1) {
    int t2 = __shfl_up(s, d);
    if (lane >= d) s += t2;
  }
  if (lane < nb) bsum[lane] = s - v;
  if (lane == 63) bsum[nb] = s;
}

// merged scan phase 3: blockIdx.y = 0 edges, 1 nodes
__global__ void scan3_kernel(
    const int* __restrict__ cnt_e, int* __restrict__ off_e, int* __restrict__ cur_e,
    float* __restrict__ recip_e, const int* __restrict__ bsum_e, int ne,
    const int* __restrict__ cnt_n, int* __restrict__ off_n, int* __restrict__ cur_n,
    float* __restrict__ recip_n, const int* __restrict__ bsum_n, int nn) {
  const int* cnt; int* off; int* cur; float* recip; const int* bsum; int n;
  if (blockIdx.y == 0) { cnt = cnt_e; off = off_e; cur = cur_e; recip = recip_e; bsum = bsum_e; n = ne; }
  else                 { cnt = cnt_n; off = off_n; cur = cur_n; recip = recip_n; bsum = bsum_n; n = nn; }
  const int i = blockIdx.x * blockDim.x + threadIdx.x;
  if (i < n) {
    const int o = off[i] + bsum[i >> 10];
    off[i] = o;
    cur[i] = o;
    recip[i] = 1.0f / fmaxf((float)cnt[i], 1.0f);
  }
  if (i == 0) off[n] = bsum[(n + 1023) >> 10];
}

__global__ void fill_kernel(const int* __restrict__ ni, const int* __restrict__ ei,
                            int* __restrict__ cur_n, int* __restrict__ cur_e,
                            int* __restrict__ lst_n, int* __restrict__ lst_e, int nnz) {
  int i = blockIdx.x * blockDim.x + threadIdx.x;
  if (i < nnz) {
    int n = ni[i], e = ei[i];
    lst_e[atomicAdd(&cur_e[e], 1)] = n;
    lst_n[atomicAdd(&cur_n[n], 1)] = e;
  }
}

// ---------------- batched weight prep (6 jobs in one launch) ----------------

__global__ void prep_kernel(const float* __restrict__ encW0, const float* __restrict__ encW1,
                            const float* __restrict__ Wen, const float* __restrict__ decW0,
                            const float* __restrict__ decW1, const float* __restrict__ Wne,
                            u16* __restrict__ encW0T, u16* __restrict__ encW1T,
                            u16* __restrict__ WenT, u16* __restrict__ decW0T,
                            u16* __restrict__ decW1T, u16* __restrict__ WneB) {
  const int job = blockIdx.y;
  const int i = blockIdx.x * 256 + threadIdx.x;
  const float* src; u16* dst; int K = LATD, N = LATD; bool tr = true;
  switch (job) {
    case 0: src = encW0; dst = encW0T; K = OBSD; break;
    case 1: src = encW1; dst = encW1T; break;
    case 2: src = Wen;   dst = WenT;   break;
    case 3: src = decW0; dst = decW0T; break;
    case 4: src = decW1; dst = decW1T; N = OBSD; break;
    default: src = Wne;  dst = WneB;   tr = false; break;
  }
  if (i >= K * N) return;
  if (tr) {
    const int k = i / N, n = i - k * N;
    dst[n * K + k] = f2b(src[i]);
  } else {
    dst[i] = f2b(src[i]);
  }
}

__global__ void to_bf16_kernel(const float* __restrict__ src, u16* __restrict__ dst, int n) {
  int i = (blockIdx.x * blockDim.x + threadIdx.x) * 4;
  if (i >= n) return;
  float4 v = *reinterpret_cast<const float4*>(src + i);
  us4 o;
  o.x = f2b(v.x); o.y = f2b(v.y); o.z = f2b(v.z); o.w = f2b(v.w);
  *reinterpret_cast<us4*>(dst + i) = o;
}

// d = bne @ Wen + ben
__global__ void dvec_kernel(const float* __restrict__ bne, const float* __restrict__ Wen,
                            const float* __restrict__ ben, float* __restrict__ d) {
  const int j = threadIdx.x;
  float s = ben[j];
  for (int k = 0; k < LATD; ++k) s += bne[k] * Wen[k * LATD + j];
  d[j] = s;
}

// ---------------- edge segment mean (8-deep pipelined gather) ----------------

template <int FP8SRC>
__global__ __launch_bounds__(256) void agg_kernel(const void* __restrict__ src,
                                                  const int* __restrict__ off,
                                                  const int* __restrict__ lst,
                                                  const float* __restrict__ recip,
                                                  u16* __restrict__ dst, int nseg) {
  constexpr int GW = FP8SRC ? 16 : 32;
  constexpr int EPL = LATD / GW;  // 16 or 8
  const int t = threadIdx.x;
  const int gl = t & (GW - 1);
  const int seg = blockIdx.x * (256 / GW) + (t / GW);
  if (seg >= nseg) return;
  const int s = off[seg], e = off[seg + 1];
  float a[EPL] = {};
  int p = s;
  if constexpr (FP8SRC) {
    for (; p + 8 <= e; p += 8) {
      u32x4 w[8];
#pragma unroll
      for (int q = 0; q < 8; ++q)
        w[q] = *(const u32x4*)((const u8*)src + (size_t)lst[p + q] * LATD + gl * 16);
#pragma unroll
      for (int q = 0; q < 8; ++q) {
        float f[16];
        fp8_dec16(w[q], f);
#pragma unroll
        for (int j = 0; j < 16; ++j) a[j] += f[j];
      }
    }
    for (; p + 4 <= e; p += 4) {
      u32x4 w[4];
#pragma unroll
      for (int q = 0; q < 4; ++q)
        w[q] = *(const u32x4*)((const u8*)src + (size_t)lst[p + q] * LATD + gl * 16);
#pragma unroll
      for (int q = 0; q < 4; ++q) {
        float f[16];
        fp8_dec16(w[q], f);
#pragma unroll
        for (int j = 0; j < 16; ++j) a[j] += f[j];
      }
    }
    for (; p < e; ++p) {
      const u32x4 w = *(const u32x4*)((const u8*)src + (size_t)lst[p] * LATD + gl * 16);
      float f[16];
      fp8_dec16(w, f);
#pragma unroll
      for (int j = 0; j < 16; ++j) a[j] += f[j];
    }
  } else {
    for (; p + 8 <= e; p += 8) {
      us8 v[8];
#pragma unroll
      for (int q = 0; q < 8; ++q)
        v[q] = *(const us8*)((const u16*)src + (size_t)lst[p + q] * LATD + gl * 8);
#pragma unroll
      for (int q = 0; q < 8; ++q)
#pragma unroll
        for (int j = 0; j < 8; ++j) a[j] += b2f(v[q][j]);
    }
    for (; p + 4 <= e; p += 4) {
      us8 v[4];
#pragma unroll
      for (int q = 0; q < 4; ++q)
        v[q] = *(const us8*)((const u16*)src + (size_t)lst[p + q] * LATD + gl * 8);
#pragma unroll
      for (int q = 0; q < 4; ++q)
#pragma unroll
        for (int j = 0; j < 8; ++j) a[j] += b2f(v[q][j]);
    }
    for (; p < e; ++p) {
      const us8 v = *(const us8*)((const u16*)src + (size_t)lst[p] * LATD + gl * 8);
#pragma unroll
      for (int j = 0; j < 8; ++j) a[j] += b2f(v[j]);
    }
  }
  const float rc = recip[seg];
  const size_t base = (size_t)seg * LATD + gl * EPL;
  if constexpr (FP8SRC) {
    us16 o;
#pragma unroll
    for (int j = 0; j < 16; ++j) o[j] = f2b(a[j] * rc);
    *(us16*)(dst + base) = o;
  } else {
    us8 o;
#pragma unroll
    for (int j = 0; j < 8; ++j) o[j] = f2b(a[j] * rc);
    *(us8*)(dst + base) = o;
  }
}

// ---------------- fused node-gather + RK epilogue (4-deep pipelined gather) ----------------

template <int STAGE>
__global__ __launch_bounds__(256) void aggn_epi_kernel(
    const void* __restrict__ G, const int* __restrict__ off, const int* __restrict__ lst,
    const float* __restrict__ recip, const float* __restrict__ dvec,
    u16* __restrict__ ub, const u8* __restrict__ k2s, const u8* __restrict__ k3s,
    u8* __restrict__ kout8, u16* __restrict__ zhi, float c) {
  constexpr int GW = (STAGE == 0) ? 32 : 16;
  constexpr int EPL = LATD / GW;  // 8 or 16
  const int t = threadIdx.x;
  const int gl = t & (GW - 1);
  const int node = blockIdx.x * (256 / GW) + (t / GW);
  if (node >= NN) return;
  const int s = off[node], e = off[node + 1];
  float v[EPL] = {};
  int p = s;
  if constexpr (STAGE == 0) {
    for (; p + 4 <= e; p += 4) {
      us8 g[4];
#pragma unroll
      for (int q = 0; q < 4; ++q)
        g[q] = *(const us8*)((const u16*)G + (size_t)lst[p + q] * LATD + gl * 8);
#pragma unroll
      for (int q = 0; q < 4; ++q)
#pragma unroll
        for (int j = 0; j < 8; ++j) v[j] += b2f(g[q][j]);
    }
    for (; p < e; ++p) {
      const us8 g = *(const us8*)((const u16*)G + (size_t)lst[p] * LATD + gl * 8);
#pragma unroll
      for (int j = 0; j < 8; ++j) v[j] += b2f(g[j]);
    }
  } else {
    for (; p + 4 <= e; p += 4) {
      u32x4 w[4];
#pragma unroll
      for (int q = 0; q < 4; ++q)
        w[q] = *(const u32x4*)((const u8*)G + (size_t)lst[p + q] * LATD + gl * 16);
#pragma unroll
      for (int q = 0; q < 4; ++q) {
        float f[16];
        fp8_dec16(w[q], f);
#pragma unroll
        for (int j = 0; j < 16; ++j) v[j] += f[j];
      }
    }
    for (; p < e; ++p) {
      const u32x4 w = *(const u32x4*)((const u8*)G + (size_t)lst[p] * LATD + gl * 16);
      float f[16];
      fp8_dec16(w, f);
#pragma unroll
      for (int j = 0; j < 16; ++j) v[j] += f[j];
    }
  }
  const float rc = recip[node];
  const size_t base = (size_t)node * LATD + gl * EPL;
  const float dt6 = 0.125f / 6.0f;

  if constexpr (STAGE == 0) {
    float kv[8];
    us8 uo;
#pragma unroll
    for (int j = 0; j < 8; ++j) {
      const float u = v[j] * rc + dvec[gl * 8 + j];
      uo[j] = f2b(u);
      kv[j] = fast_tanh(u);
    }
    *(us8*)(ub + base) = uo;
    u32x2 kp;
    kp[0] = fp8_enc4(kv);
    kp[1] = fp8_enc4(kv + 4);
    *(u32x2*)(kout8 + base) = kp;
  } else if constexpr (STAGE == 1) {
    const us16 uv = *(const us16*)(ub + base);
    float kv[16];
#pragma unroll
    for (int j = 0; j < 16; ++j)
      kv[j] = fast_tanh(b2f(uv[j]) + c * (v[j] * rc));
    u32x4 kp;
#pragma unroll
    for (int q = 0; q < 4; ++q) kp[q] = fp8_enc4(kv + q * 4);
    *(u32x4*)(kout8 + base) = kp;
  } else {  // STAGE 3
    const us16 uv = *(const us16*)(ub + base);
    const u32x4 w2 = *(const u32x4*)(k2s + base);
    const u32x4 w3 = *(const u32x4*)(k3s + base);
    const us16 zh = *(const us16*)(zhi + base);
    float f2[16], f3[16];
    fp8_dec16(w2, f2);
    fp8_dec16(w3, f3);
    us16 ho;
#pragma unroll
    for (int j = 0; j < 16; ++j) {
      const float u = b2f(uv[j]);
      const float k1 = fast_tanh(u);
      const float k4 = fast_tanh(u + c * (v[j] * rc));
      const float zn = b2f(zh[j]) + dt6 * (k1 + 2.0f * f2[j] + 2.0f * f3[j] + k4);
      ho[j] = f2b(zn);
    }
    *(us16*)(zhi + base) = ho;
  }
}

// ---------------- 64x128-tile edge GEMM: G = A[NE x 256] @ WcT^T, no bias ----------------

template <int OUT8>
__global__ __launch_bounds__(256) void gemm64_kernel(
    const u16* __restrict__ A, const u16* __restrict__ BT,
    u16* __restrict__ Gb, u8* __restrict__ Gf8) {
  __shared__ char smem[4 * 16 * 66 * 4];
  u16* lA = (u16*)smem;                   // 64 x 32 = 4KB
  u16* lB = (u16*)(smem + 4096);          // 128 x 32 = 8KB
  const int t = threadIdx.x;
  const int m0 = blockIdx.x * 64, n0 = blockIdx.y * 128;
  const int srow = t >> 2;
  const int gslot = (t & 3) ^ ((srow >> 1) & 3);

  int ar = m0 + srow; if (ar > NE - 1) ar = NE - 1;
  const u16* gA = A + (size_t)ar * LATD + gslot * 8;
  const u16* gB0 = BT + (size_t)(n0 + srow) * LATD + gslot * 8;
  const u16* gB1 = BT + (size_t)(n0 + 64 + srow) * LATD + gslot * 8;
  char* lAd = (char*)lA + t * 16;
  char* lBd0 = (char*)lB + t * 16;
  char* lBd1 = lBd0 + 4096;

  const int lane = t & 63, wid = t >> 6;
  const int lrow = lane & 15, kg = lane >> 4;

  f32x4 acc[4][2] = {};
  const char* lAb = (const char*)lA;
  const char* lBb = (const char*)lB;

  for (int c = 0; c < 8; ++c) {
    const int kk = c * 32;
    async16(gA + kk, lAd);
    async16(gB0 + kk, lBd0);
    async16(gB1 + kk, lBd1);
    __syncthreads();
    bf16x8 af[4], bg[2];
#pragma unroll
    for (int i = 0; i < 4; ++i) {
      const int rA = i * 16 + lrow;
      af[i] = *(const bf16x8*)(lAb + rA * 64 + (((kg ^ (rA >> 1)) & 3) << 4));
    }
#pragma unroll
    for (int j = 0; j < 2; ++j) {
      const int rB = wid * 32 + j * 16 + lrow;
      bg[j] = *(const bf16x8*)(lBb + rB * 64 + (((kg ^ (rB >> 1)) & 3) << 4));
    }
#pragma unroll
    for (int i = 0; i < 4; ++i)
#pragma unroll
      for (int j = 0; j < 2; ++j)
        acc[i][j] = __builtin_amdgcn_mfma_f32_16x16x32_bf16(af[i], bg[j], acc[i][j], 0, 0, 0);
    __syncthreads();
  }

  float* stage = (float*)smem + wid * (16 * 66);
  const int rr = lane >> 2;
  const int c0 = (lane & 3) * 8;

#pragma unroll
  for (int ti = 0; ti < 4; ++ti) {
#pragma unroll
    for (int tj = 0; tj < 2; ++tj)
#pragma unroll
      for (int j = 0; j < 4; ++j)
        stage[(kg * 4 + j) * 66 + tj * 16 + lrow] = acc[ti][tj][j];
    const int gr = m0 + ti * 16 + rr;
    if (gr < NE) {
      const int gc = n0 + wid * 32 + c0;
      const size_t idx = (size_t)gr * LATD + gc;
      float v[8];
      *(float4*)v = *(const float4*)&stage[rr * 66 + c0];
      *(float4*)(v + 4) = *(const float4*)&stage[rr * 66 + c0 + 4];
      if constexpr (OUT8) {
        u32x2 kp;
        kp[0] = fp8_enc4(v);
        kp[1] = fp8_enc4(v + 4);
        *(u32x2*)(Gf8 + idx) = kp;
      } else {
        us8 o;
#pragma unroll
        for (int e2 = 0; e2 < 8; ++e2) o[e2] = f2b(v[e2]);
        *(us8*)(Gb + idx) = o;
      }
    }
  }
}

// ---------------- 128-tile MFMA GEMM (enc/dec/prep) ----------------

enum { EPI_RELU_BF16, EPI_BF16, EPI_F32 };

template <int MODE>
__global__ __launch_bounds__(256) void gemm_kernel(
    const u16* __restrict__ A, const u16* __restrict__ BT, const float* __restrict__ bias,
    int M, int N, int K,
    u16* __restrict__ outb, float* __restrict__ outf) {
  __shared__ char smem[4 * 16 * 66 * 4];
  u16* lA = (u16*)smem;
  u16* lB = (u16*)(smem + 8192);
  const int t = threadIdx.x;
  const int m0 = blockIdx.x * 128, n0 = blockIdx.y * 128;
  const int srow = t >> 2;
  const int gslot = (t & 3) ^ ((srow >> 1) & 3);

  int ar0 = m0 + srow;      if (ar0 > M - 1) ar0 = M - 1;
  int ar1 = m0 + srow + 64; if (ar1 > M - 1) ar1 = M - 1;
  const u16* gA0 = A + (size_t)ar0 * K + gslot * 8;
  const u16* gA1 = A + (size_t)ar1 * K + gslot * 8;
  const u16* gB0 = BT + (size_t)(n0 + srow) * K + gslot * 8;
  const u16* gB1 = BT + (size_t)(n0 + srow + 64) * K + gslot * 8;
  char* lAd0 = (char*)lA + t * 16; char* lAd1 = lAd0 + 4096;
  char* lBd0 = (char*)lB + t * 16; char* lBd1 = lBd0 + 4096;

  const int lane = t & 63, wid = t >> 6;
  const int wm = wid >> 1, wn = wid & 1;
  const int lrow = lane & 15, kg = lane >> 4;

  f32x4 acc[4][4] = {};
  const char* lAb = (const char*)lA;
  const char* lBb = (const char*)lB;

  for (int kk = 0; kk < K; kk += 32) {
    async16(gA0 + kk, lAd0);
    async16(gA1 + kk, lAd1);
    async16(gB0 + kk, lBd0);
    async16(gB1 + kk, lBd1);
    __syncthreads();
    bf16x8 af[4], bg[4];
#pragma unroll
    for (int i = 0; i < 4; ++i) {
      int rA = wm * 64 + i * 16 + lrow;
      af[i] = *(const bf16x8*)(lAb + rA * 64 + (((kg ^ (rA >> 1)) & 3) << 4));
      int rB = wn * 64 + i * 16 + lrow;
      bg[i] = *(const bf16x8*)(lBb + rB * 64 + (((kg ^ (rB >> 1)) & 3) << 4));
    }
#pragma unroll
    for (int i = 0; i < 4; ++i)
#pragma unroll
      for (int j = 0; j < 4; ++j)
        acc[i][j] = __builtin_amdgcn_mfma_f32_16x16x32_bf16(af[i], bg[j], acc[i][j], 0, 0, 0);
    __syncthreads();
  }

  float* stage = (float*)smem + wid * (16 * 66);
  const int rr = lane >> 3;
  const int c0 = (lane & 7) * 8;

#pragma unroll
  for (int ti = 0; ti < 4; ++ti) {
#pragma unroll
    for (int tj = 0; tj < 4; ++tj) {
      const float bv = bias[n0 + wn * 64 + tj * 16 + lrow];
#pragma unroll
      for (int j = 0; j < 4; ++j)
        stage[(kg * 4 + j) * 66 + tj * 16 + lrow] = acc[ti][tj][j] + bv;
    }
#pragma unroll
    for (int pass = 0; pass < 2; ++pass) {
      const int r = pass * 8 + rr;
      const int gr = m0 + wm * 64 + ti * 16 + r;
      if (gr >= M) continue;
      const int gc = n0 + wn * 64 + c0;
      const size_t idx = (size_t)gr * N + gc;
      float v[8];
      *(float4*)v = *(const float4*)&stage[r * 66 + c0];
      *(float4*)(v + 4) = *(const float4*)&stage[r * 66 + c0 + 4];

      if constexpr (MODE == EPI_RELU_BF16 || MODE == EPI_BF16) {
        us8 o;
#pragma unroll
        for (int e2 = 0; e2 < 8; ++e2)
          o[e2] = f2b(MODE == EPI_RELU_BF16 ? fmaxf(v[e2], 0.0f) : v[e2]);
        *(us8*)(outb + idx) = o;
      } else {
        *(float4*)(outf + idx) = *(float4*)v;
        *(float4*)(outf + idx + 4) = *(float4*)(v + 4);
      }
    }
  }
}

// ---------------- launch ----------------

extern "C" void kernel_launch(void* const* d_in, const int* in_sizes, int n_in,
                              void* d_out, int out_size, void* d_ws, size_t ws_size,
                              hipStream_t stream) {
  const float* X = (const float*)d_in[0];
  const float* encW0 = (const float*)d_in[1];
  const float* encb0 = (const float*)d_in[2];
  const float* encW1 = (const float*)d_in[3];
  const float* encb1 = (const float*)d_in[4];
  const float* Wne = (const float*)d_in[5];
  const float* bne = (const float*)d_in[6];
  const float* Wen = (const float*)d_in[7];
  const float* ben = (const float*)d_in[8];
  const float* decW0 = (const float*)d_in[9];
  const float* decb0 = (const float*)d_in[10];
  const float* decW1 = (const float*)d_in[11];
  const float* decb1 = (const float*)d_in[12];
  const int* node_idx = (const int*)d_in[13];
  const int* edge_idx = (const int*)d_in[14];
  float* out = (float*)d_out;

  char* p = (char*)d_ws;
  auto alloc = [&](size_t bytes) {
    char* r = p;
    p += (bytes + 255) & ~(size_t)255;
    return r;
  };
  u16* zhi      = (u16*)alloc((size_t)NN * LATD * 2);
  u16* ub       = (u16*)alloc((size_t)NN * LATD * 2);
  u16* h1b      = (u16*)alloc((size_t)NN * LATD * 2);
  u8*  pA       = (u8*)alloc((size_t)NN * LATD);
  u8*  pB       = (u8*)alloc((size_t)NN * LATD);
  u16* eagg     = (u16*)alloc((size_t)NE * LATD * 2);
  u16* Gb       = (u16*)alloc((size_t)NE * LATD * 2);
  u8*  Gf8      = (u8*)alloc((size_t)NE * LATD);
  u16* encW0T   = (u16*)alloc((size_t)OBSD * LATD * 2);
  u16* encW1T   = (u16*)alloc((size_t)LATD * LATD * 2);
  u16* WneB     = (u16*)alloc((size_t)LATD * LATD * 2);
  u16* WenT     = (u16*)alloc((size_t)LATD * LATD * 2);
  u16* WcT      = (u16*)alloc((size_t)LATD * LATD * 2);
  u16* decW0T   = (u16*)alloc((size_t)LATD * LATD * 2);
  u16* decW1T   = (u16*)alloc((size_t)LATD * OBSD * 2);
  float* dvec   = (float*)alloc(LATD * 4);
  float* zeros  = (float*)alloc(LATD * 4);
  int* cnt      = (int*)alloc((size_t)(NE + NN) * 4);
  int* cnt_e = cnt; int* cnt_n = cnt + NE;
  int* off_e    = (int*)alloc((size_t)(NE + 1) * 4);
  int* off_n    = (int*)alloc((size_t)(NN + 1) * 4);
  int* cur_e    = (int*)alloc((size_t)NE * 4);
  int* cur_n    = (int*)alloc((size_t)NN * 4);
  int* lst_e    = (int*)alloc((size_t)NNZC * 4);
  int* lst_n    = (int*)alloc((size_t)NNZC * 4);
  float* recip_e = (float*)alloc((size_t)NE * 4);
  float* recip_n = (float*)alloc((size_t)NN * 4);
  int* bsum_e   = (int*)alloc(16 * 4);
  int* bsum_n   = (int*)alloc(64 * 4);

  size_t needed = (size_t)(p - (char*)d_ws);
  if (needed > ws_size) {
    hipMemsetAsync(d_out, 0x7F, (size_t)out_size * 4, stream);
    return;
  }

  const int nbe = (NE + 1023) / 1024, nbn = (NN + 1023) / 1024;

  // CSR build (merged scans)
  hipMemsetAsync(cnt, 0, (size_t)(NE + NN) * 4, stream);
  count_kernel<<<(NNZC + 255) / 256, 256, 0, stream>>>(node_idx, edge_idx, cnt_n, cnt_e, NNZC);
  scan1_kernel<<<nbe + nbn, 1024, 0, stream>>>(cnt_e, off_e, bsum_e, NE, nbe,
                                               cnt_n, off_n, bsum_n, NN);
  scan2_kernel<<<1, 128, 0, stream>>>(bsum_e, nbe, bsum_n, nbn);
  scan3_kernel<<<dim3((NN + 255) / 256, 2), 256, 0, stream>>>(
      cnt_e, off_e, cur_e, recip_e, bsum_e, NE,
      cnt_n, off_n, cur_n, recip_n, bsum_n, NN);
  fill_kernel<<<(NNZC + 255) / 256, 256, 0, stream>>>(node_idx, edge_idx, cur_n, cur_e, lst_n, lst_e, NNZC);

  // weight prep (batched) + dvec + Wc
  prep_kernel<<<dim3(256, 6), 256, 0, stream>>>(encW0, encW1, Wen, decW0, decW1, Wne,
                                                encW0T, encW1T, WenT, decW0T, decW1T, WneB);
  hipMemsetAsync(zeros, 0, LATD * 4, stream);
  dvec_kernel<<<1, LATD, 0, stream>>>(bne, Wen, ben, dvec);
  gemm_kernel<EPI_BF16><<<dim3(2, 2), 256, 0, stream>>>(WenT, WneB, zeros, LATD, LATD, LATD,
                                                        WcT, nullptr);

  const dim3 blk(256);
  const dim3 g50((NN + 127) / 128, LATD / 128);   // (391, 2)
  const dim3 gdec((NN + 127) / 128, OBSD / 128);  // (391, 1)
  const dim3 g64((NE + 63) / 64, 2);              // (157, 2) = 314 blocks
  const dim3 gae32((NE + 7) / 8);                 // 1250 (bf16 src)
  const dim3 gae16((NE + 15) / 16);               // 625  (fp8 src)
  const dim3 gan32((NN + 7) / 8);                 // 6250 (stage 0)
  const dim3 gan16((NN + 15) / 16);               // 3125 (stages 1-3)

  // encode: h1 = relu(X@W0+b0) ; z = h1@W1+b1 -> zhi (bf16)
  to_bf16_kernel<<<(NN * OBSD / 4 + 255) / 256, 256, 0, stream>>>(X, (u16*)pA, NN * OBSD);
  gemm_kernel<EPI_RELU_BF16><<<g50, blk, 0, stream>>>((u16*)pA, encW0T, encb0, NN, LATD, OBSD,
                                                      h1b, nullptr);
  gemm_kernel<EPI_BF16><<<g50, blk, 0, stream>>>(h1b, encW1T, encb1, NN, LATD, LATD,
                                                 zhi, nullptr);

  // RK4: agg_e -> edge GEMM (64-tile) -> fused node-gather+epilogue
  // fp8 k planes ping-pong: k1->pA, k2->pB, k3->pA; stage3 reads k2=pB, k3=pA
  for (int s = 0; s < NSTEPS; ++s) {
    // k=0
    agg_kernel<0><<<gae32, blk, 0, stream>>>(zhi, off_e, lst_e, recip_e, eagg, NE);
    gemm64_kernel<0><<<g64, blk, 0, stream>>>(eagg, WcT, Gb, nullptr);
    aggn_epi_kernel<0><<<gan32, blk, 0, stream>>>(Gb, off_n, lst_n, recip_n, dvec,
                                                  ub, nullptr, nullptr, pA, zhi, 0.f);
    // k=1
    agg_kernel<1><<<gae16, blk, 0, stream>>>(pA, off_e, lst_e, recip_e, eagg, NE);
    gemm64_kernel<1><<<g64, blk, 0, stream>>>(eagg, WcT, nullptr, Gf8);
    aggn_epi_kernel<1><<<gan16, blk, 0, stream>>>(Gf8, off_n, lst_n, recip_n, dvec,
                                                  ub, nullptr, nullptr, pB, zhi, 0.0625f);
    // k=2
    agg_kernel<1><<<gae16, blk, 0, stream>>>(pB, off_e, lst_e, recip_e, eagg, NE);
    gemm64_kernel<1><<<g64, blk, 0, stream>>>(eagg, WcT, nullptr, Gf8);
    aggn_epi_kernel<1><<<gan16, blk, 0, stream>>>(Gf8, off_n, lst_n, recip_n, dvec,
                                                  ub, nullptr, nullptr, pA, zhi, 0.0625f);
    // k=3
    agg_kernel<1><<<gae16, blk, 0, stream>>>(pA, off_e, lst_e, recip_e, eagg, NE);
    gemm64_kernel<1><<<g64, blk, 0, stream>>>(eagg, WcT, nullptr, Gf8);
    aggn_epi_kernel<3><<<gan16, blk, 0, stream>>>(Gf8, off_n, lst_n, recip_n, dvec,
                                                  ub, pB, pA, nullptr, zhi, 0.125f);
  }

  // decode (zhi = bf16(z_final))
  gemm_kernel<EPI_RELU_BF16><<<g50, blk, 0, stream>>>(zhi, decW0T, decb0, NN, LATD, LATD,
                                                      h1b, nullptr);
  gemm_kernel<EPI_F32><<<gdec, blk, 0, stream>>>(h1b, decW1T, decb1, NN, OBSD, LATD,
                                                 nullptr, out);
}